// Round 15
// baseline (1764.823 us; speedup 1.0000x reference)
//
#include <hip/hip_runtime.h>
#include <hip/hip_bf16.h>

#define BB 16
#define NN 4096
#define NPOINTS 1024
#define KK 32
#define NPTS (BB*NPOINTS)        // 16384
#define NWN  (BB*NPOINTS*KK)     // 524288
#define EPSF 1e-5f
#define SGBLK 512
#define SGIT  4
#define NSLOT 64

typedef unsigned short u16;
typedef u16  u16x8 __attribute__((ext_vector_type(8)));
typedef u16  u16x4 __attribute__((ext_vector_type(4)));
typedef short s16x8 __attribute__((ext_vector_type(8)));
typedef float f32x4 __attribute__((ext_vector_type(4)));
typedef float f32x4u __attribute__((ext_vector_type(4), aligned(4)));

__device__ __forceinline__ float bf(u16 u){
  union { unsigned int i; float f; } v; v.i = ((unsigned int)u) << 16; return v.f;
}
__device__ __forceinline__ u16 f2b(float f){
  __hip_bfloat16 h = __float2bfloat16(f);
  union { __hip_bfloat16 hh; u16 u; } v; v.hh = h; return v.u;
}

// F layout (folded weights): [0..47] w0f, [48..63] b0f, [64..319] w1f,
// [320..335] b1f, [336..1359] w2f, [1360..1423] b2f
// npw: transposed position space q = o*64 + i  (original channel ch = i*64 + o)
// w1Bg[64][8], w2Bg[4][64][8]: per-lane bf16 MFMA B-fragments (ic zero-padded to 32)
// slotC[NSLOT][8192]: per-slot channel stat partials (s at [0..4095], q at [4096..8191])

// ---------------- k_init ----------------
__global__ __launch_bounds__(256) void k_init(const float* xyz, const int* didx, float* out,
                                              const float* lw, u16* lwbt){
  int t = threadIdx.x;
  if (blockIdx.x < 64){
    int p = blockIdx.x * 256 + t;
    int b = p >> 10;
    int idx = didx[p];
    const float* src = xyz + ((size_t)(b * NN + idx)) * 3;
    float* dst = out + (size_t)p * 3;
    dst[0] = src[0]; dst[1] = src[1]; dst[2] = src[2];
  } else {
    __shared__ float T[64][65];
    int ib = blockIdx.x - 64;
    int kb = ib * 64;
    {
      int k = t >> 2, c4 = t & 3;
      #pragma unroll
      for (int j = 0; j < 4; ++j)
        *(f32x4*)&T[k][c4*16 + j*4] = *(const f32x4*)(lw + (size_t)(kb + k)*64 + c4*16 + j*4);
    }
    __syncthreads();
    {
      int n = t >> 2, k4 = t & 3;
      #pragma unroll
      for (int j = 0; j < 16; ++j){
        int k = k4*16 + j;
        lwbt[(size_t)n*4096 + k*64 + ib] = f2b(T[k][n]);
      }
    }
  }
}

// ---------------- k_stat0 ----------------
__global__ __launch_bounds__(256) void k_stat0(const float* lc, float* PA){
  int t = threadIdx.x;
  float a[9];
  #pragma unroll
  for (int r = 0; r < 9; ++r) a[r] = 0.f;
  size_t base = (size_t)blockIdx.x * 1024 + t;
  for (int ip = 0; ip < 4; ++ip){
    size_t p = base + (size_t)ip * 256;
    float x0 = lc[p*3], x1 = lc[p*3+1], x2 = lc[p*3+2];
    a[0]+=x0; a[1]+=x1; a[2]+=x2;
    a[3]+=x0*x0; a[4]+=x0*x1; a[5]+=x0*x2;
    a[6]+=x1*x1; a[7]+=x1*x2; a[8]+=x2*x2;
  }
  #pragma unroll
  for (int m = 1; m < 64; m <<= 1){
    #pragma unroll
    for (int r = 0; r < 9; ++r) a[r] += __shfl_xor(a[r], m);
  }
  if ((t & 63) == 0){
    float* dst = PA + (size_t)(blockIdx.x*4 + (t>>6)) * 16;
    f32x4 v0 = {a[0],a[1],a[2],a[3]}, v1 = {a[4],a[5],a[6],a[7]}, v2 = {a[8],0.f,0.f,0.f};
    *(f32x4*)dst = v0; *(f32x4*)(dst+4) = v1; *(f32x4*)(dst+8) = v2;
  }
}

// ---------------- k_red0 ----------------
__global__ __launch_bounds__(256) void k_red0(const float* PA, const float* w0, const float* b0,
                                              const float* g0, const float* be0, float* F){
  __shared__ float ms[12];
  __shared__ float a0sh[16];
  int t = threadIdx.x;
  if (t < 12){
    float s0=0,s1=0,s2=0,s3=0;
    const float* p = PA + t;
    for (int r = 0; r < 2048; r += 4){
      s0 += p[(size_t)(r+0)*16]; s1 += p[(size_t)(r+1)*16];
      s2 += p[(size_t)(r+2)*16]; s3 += p[(size_t)(r+3)*16];
    }
    ms[t] = (s0+s1)+(s2+s3);
  }
  __syncthreads();
  if (t < 16){
    float wx = w0[t*3], wy = w0[t*3+1], wz = w0[t*3+2], bb = b0[t];
    float lin = wx*ms[0] + wy*ms[1] + wz*ms[2];
    float quad = wx*wx*ms[3] + wy*wy*ms[6] + wz*wz*ms[8]
               + 2.f*(wx*wy*ms[4] + wx*wz*ms[5] + wy*wz*ms[7]);
    float S = lin + (float)NWN * bb;
    float Q = quad + 2.f*bb*lin + (float)NWN*bb*bb;
    float m = S * (1.f/NWN);
    float v = Q * (1.f/NWN) - m*m;
    float a = g0[t] * rsqrtf(v + EPSF);
    float d = be0[t] - m*a;
    a0sh[t] = a;
    F[48+t] = a*bb + d;
  }
  __syncthreads();
  if (t < 48) F[t] = a0sh[t/3] * w0[t];
}

// ---------------- k_statG ----------------
template<bool L2>
__global__ __launch_bounds__(256) void k_statG(const float* lc, const float* F, float* PB){
  __shared__ f32x4 w0p[16];
  __shared__ float w1s[256], b1fs[16];
  __shared__ __align__(16) u16 Ht[4][16*72];
  __shared__ float GS[4][16][17];
  __shared__ float SHs[4][16];
  int t = threadIdx.x;
  int w = t >> 6, l = t & 63;
  if (t < 16){
    f32x4 wv = {F[t*3], F[t*3+1], F[t*3+2], F[48+t]};
    w0p[t] = wv;
    if (L2) b1fs[t] = F[320+t];
  }
  if (L2) w1s[t] = F[64+t];
  __syncthreads();
  f32x4 acc = {0.f,0.f,0.f,0.f};
  float sh[16];
  #pragma unroll
  for (int r = 0; r < 16; ++r) sh[r] = 0.f;
  u16* Hw = &Ht[w][0];
  for (int it = 0; it < SGIT; ++it){
    size_t p = (size_t)blockIdx.x * (SGIT*256) + (size_t)it*256 + w*64 + l;
    float x0 = lc[p*3], x1 = lc[p*3+1], x2 = lc[p*3+2];
    float h[16];
    #pragma unroll
    for (int oc = 0; oc < 16; ++oc){
      f32x4 wv = w0p[oc];
      h[oc] = fmaxf(0.f, wv.x*x0 + wv.y*x1 + wv.z*x2 + wv.w);
    }
    if (L2){
      float h1[16];
      #pragma unroll
      for (int oc = 0; oc < 16; ++oc){
        const f32x4* wr = (const f32x4*)&w1s[oc*16];
        f32x4 wa = wr[0], wb = wr[1], wc = wr[2], wd = wr[3];
        float y = b1fs[oc];
        y += wa.x*h[0]  + wa.y*h[1]  + wa.z*h[2]  + wa.w*h[3];
        y += wb.x*h[4]  + wb.y*h[5]  + wb.z*h[6]  + wb.w*h[7];
        y += wc.x*h[8]  + wc.y*h[9]  + wc.z*h[10] + wc.w*h[11];
        y += wd.x*h[12] + wd.y*h[13] + wd.z*h[14] + wd.w*h[15];
        h1[oc] = fmaxf(0.f, y);
      }
      #pragma unroll
      for (int oc = 0; oc < 16; ++oc) h[oc] = h1[oc];
    }
    #pragma unroll
    for (int oc = 0; oc < 16; ++oc) sh[oc] += h[oc];
    #pragma unroll
    for (int c = 0; c < 16; ++c) Hw[c*72 + l] = f2b(h[c]);
    __syncthreads();
    #pragma unroll
    for (int tt = 0; tt < 2; ++tt){
      s16x8 af = *(const s16x8*)&Hw[(l & 15)*72 + tt*32 + (l >> 4)*8];
      acc = __builtin_amdgcn_mfma_f32_16x16x32_bf16(af, af, acc, 0, 0, 0);
    }
    __syncthreads();
  }
  #pragma unroll
  for (int r = 0; r < 4; ++r)
    GS[w][(l>>4)*4 + r][l & 15] = acc[r];
  #pragma unroll
  for (int m = 1; m < 64; m <<= 1){
    #pragma unroll
    for (int r = 0; r < 16; ++r) sh[r] += __shfl_xor(sh[r], m);
  }
  if (l == 0){
    #pragma unroll
    for (int r = 0; r < 16; ++r) SHs[w][r] = sh[r];
  }
  __syncthreads();
  {
    int i = t >> 4, j = t & 15;
    float g = GS[0][i][j] + GS[1][i][j] + GS[2][i][j] + GS[3][i][j];
    PB[(size_t)blockIdx.x*272 + t] = g;
    if (t < 16)
      PB[(size_t)blockIdx.x*272 + 256 + t] = SHs[0][t]+SHs[1][t]+SHs[2][t]+SHs[3][t];
  }
}

// ---------------- k_red1 ----------------
__global__ __launch_bounds__(256) void k_red1(const float* PB, const float* w1, const float* b1,
                                              const float* g1, const float* be1, float* F,
                                              u16* w1Bg){
  __shared__ float red[272];
  __shared__ float a1sh[16];
  int t = threadIdx.x;
  for (int e = t; e < 272; e += 256){
    float s = 0.f;
    for (int r = 0; r < SGBLK; ++r) s += PB[(size_t)r*272 + e];
    red[e] = s;
  }
  __syncthreads();
  if (t < 16){
    float wv[16];
    #pragma unroll
    for (int ic = 0; ic < 16; ++ic) wv[ic] = w1[t*16+ic];
    float lin = 0.f;
    #pragma unroll
    for (int ic = 0; ic < 16; ++ic) lin += wv[ic]*red[256+ic];
    float quad = 0.f;
    for (int i = 0; i < 16; ++i){
      float ri = 0.f;
      #pragma unroll
      for (int j = 0; j < 16; ++j) ri += wv[j]*red[i*16+j];
      quad += wv[i]*ri;
    }
    float bb = b1[t];
    float S = lin + (float)NWN * bb;
    float Q = quad + 2.f*bb*lin + (float)NWN*bb*bb;
    float m = S * (1.f/NWN);
    float v = Q * (1.f/NWN) - m*m;
    float a = g1[t] * rsqrtf(v + EPSF);
    float d = be1[t] - m*a;
    a1sh[t] = a;
    F[320+t] = a*bb + d;
  }
  __syncthreads();
  F[64 + t] = a1sh[t >> 4] * w1[t];
  if (t < 64){
    int oc = t & 15, icb = (t >> 4) * 8;
    u16x8 fr;
    #pragma unroll
    for (int j = 0; j < 8; ++j){
      int ic = icb + j;
      fr[j] = (ic < 16) ? f2b(a1sh[oc] * w1[oc*16 + ic]) : (u16)0;
    }
    *(u16x8*)&w1Bg[t*8] = fr;
  }
}

// ---------------- k_red2 ----------------
__global__ __launch_bounds__(256) void k_red2(const float* PB, const float* w2, const float* b2,
                                              const float* g2, const float* be2, float* F,
                                              u16* w2Bg){
  __shared__ float red[272];
  __shared__ float a2sh[64];
  int t = threadIdx.x;
  for (int e = t; e < 272; e += 256){
    float s = 0.f;
    for (int r = 0; r < SGBLK; ++r) s += PB[(size_t)r*272 + e];
    red[e] = s;
  }
  __syncthreads();
  if (t < 64){
    float wv[16];
    #pragma unroll
    for (int ic = 0; ic < 16; ++ic) wv[ic] = w2[t*16+ic];
    float lin = 0.f;
    #pragma unroll
    for (int ic = 0; ic < 16; ++ic) lin += wv[ic]*red[256+ic];
    float quad = 0.f;
    for (int i = 0; i < 16; ++i){
      float ri = 0.f;
      #pragma unroll
      for (int j = 0; j < 16; ++j) ri += wv[j]*red[i*16+j];
      quad += wv[i]*ri;
    }
    float bb = b2[t];
    float S = lin + (float)NWN * bb;
    float Q = quad + 2.f*bb*lin + (float)NWN*bb*bb;
    float m = S * (1.f/NWN);
    float v = Q * (1.f/NWN) - m*m;
    float a = g2[t] * rsqrtf(v + EPSF);
    float d = be2[t] - m*a;
    a2sh[t] = a;
    F[1360+t] = a*bb + d;
  }
  __syncthreads();
  for (int i = t; i < 1024; i += 256) F[336+i] = a2sh[i >> 4] * w2[i];
  {
    int ot = t >> 6, lane = t & 63;
    int oc = ot*16 + (lane & 15), icb = ((lane >> 4)) * 8;
    u16x8 fr;
    #pragma unroll
    for (int j = 0; j < 8; ++j){
      int ic = icb + j;
      fr[j] = (ic < 16) ? f2b(a2sh[oc] * w2[oc*16 + ic]) : (u16)0;
    }
    *(u16x8*)&w2Bg[t*8] = fr;
  }
}

// ---------------- K5: one point per block — MFMA WeightNet + MFMA matmul + fused channel stats ----------------
__global__ __launch_bounds__(256) void k_main(const float* lcg, const int* nbrg,
    const float* points, const float* xyz, const float* F,
    const u16* w1Bg, const u16* w2Bg,
    u16* npw, float* slotC){
  __shared__ u16 Gr[32*72];                         // bf16 [k][i]
  __shared__ u16 Wr[32*72];                         // bf16 [k][o]
  __shared__ __align__(16) u16 H0bf[32*40];         // bf16 [k][ic], ic zero-padded to 32
  __shared__ __align__(16) u16 H1bf[32*40];
  __shared__ float w0c[48], b0c[16];
  int t = threadIdx.x;
  int w = t >> 6, l = t & 63;
  int point = blockIdx.x;
  int bb = point >> 10;
  // early frag loads (registers, L2-hot)
  s16x8 w1B = *(const s16x8*)&w1Bg[l*8];
  int otA = (w & 1)*2, otB = otA + 1;
  s16x8 w2BA = *(const s16x8*)&w2Bg[(otA*64 + l)*8];
  s16x8 w2BB = *(const s16x8*)&w2Bg[(otB*64 + l)*8];
  float b1f = F[320 + (l & 15)];
  float b2fA = F[1360 + otA*16 + (l & 15)];
  float b2fB = F[1360 + otB*16 + (l & 15)];
  if (t < 48) w0c[t] = F[t];
  if (t < 16) b0c[t] = F[48+t];
  // zero-pad ic 16..31 of H0bf and H1bf
  {
    int k = t >> 3, c = 16 + (t & 7)*2;
    *(unsigned int*)&H0bf[k*40 + c] = 0u;
    *(unsigned int*)&H1bf[k*40 + c] = 0u;
  }
  // gather -> Gr (wave-private rows 8w..8w+7)
  {
    int kg = w*8 + (l >> 3), c8 = l & 7;
    int n = nbrg[(size_t)point*32 + kg];
    const float* prow = points + (size_t)(bb * NN + n) * 61;
    u16x8 g;
    if (c8 < 7){
      f32x4 lo = *(const f32x4u*)(prow + c8*8);
      f32x4 hi = *(const f32x4u*)(prow + c8*8 + 4);
      g[0]=f2b(lo.x); g[1]=f2b(lo.y); g[2]=f2b(lo.z); g[3]=f2b(lo.w);
      g[4]=f2b(hi.x); g[5]=f2b(hi.y); g[6]=f2b(hi.z); g[7]=f2b(hi.w);
    } else {
      const float* xr = xyz + (size_t)(bb * NN + n) * 3;
      f32x4 lo = *(const f32x4u*)(prow + 56);
      g[0]=f2b(lo.x); g[1]=f2b(lo.y); g[2]=f2b(lo.z); g[3]=f2b(lo.w);
      g[4]=f2b(prow[60]);
      g[5]=f2b(xr[0]); g[6]=f2b(xr[1]); g[7]=f2b(xr[2]);
    }
    *(u16x8*)&Gr[kg*72 + c8*8] = g;
  }
  __syncthreads();   // (0) w0c/b0c staged before any H0 read
  // H0 -> H0bf
  {
    int k = t >> 3, oc0 = (t & 7)*2;
    const float* xp = lcg + (size_t)point*96 + k*3;
    float x0 = xp[0], x1 = xp[1], x2 = xp[2];
    #pragma unroll
    for (int e = 0; e < 2; ++e){
      int oc = oc0 + e;
      float y = w0c[oc*3]*x0 + w0c[oc*3+1]*x1 + w0c[oc*3+2]*x2 + b0c[oc];
      H0bf[k*40 + oc] = f2b(fmaxf(0.f, y));
    }
  }
  __syncthreads();   // (1) H0bf ready
  // H1 = relu(H0 · w1f^T + b1f): 2 MFMAs, waves 0-1
  if (w < 2){
    int kt = w;
    s16x8 af = *(const s16x8*)&H0bf[(kt*16 + (l & 15))*40 + (l >> 4)*8];
    f32x4 acc = {b1f, b1f, b1f, b1f};
    acc = __builtin_amdgcn_mfma_f32_16x16x32_bf16(af, w1B, acc, 0, 0, 0);
    #pragma unroll
    for (int r = 0; r < 4; ++r)
      H1bf[(kt*16 + (l >> 4)*4 + r)*40 + (l & 15)] = f2b(fmaxf(0.f, acc[r]));
  }
  __syncthreads();   // (2) H1bf ready
  // W = relu(H1 · w2f^T + b2f): 8 MFMAs across 4 waves
  {
    int kt = w >> 1;
    s16x8 af = *(const s16x8*)&H1bf[(kt*16 + (l & 15))*40 + (l >> 4)*8];
    f32x4 accA = {b2fA, b2fA, b2fA, b2fA};
    accA = __builtin_amdgcn_mfma_f32_16x16x32_bf16(af, w2BA, accA, 0, 0, 0);
    #pragma unroll
    for (int r = 0; r < 4; ++r)
      Wr[(kt*16 + (l >> 4)*4 + r)*72 + otA*16 + (l & 15)] = f2b(fmaxf(0.f, accA[r]));
    f32x4 accB = {b2fB, b2fB, b2fB, b2fB};
    accB = __builtin_amdgcn_mfma_f32_16x16x32_bf16(af, w2BB, accB, 0, 0, 0);
    #pragma unroll
    for (int r = 0; r < 4; ++r)
      Wr[(kt*16 + (l >> 4)*4 + r)*72 + otB*16 + (l & 15)] = f2b(fmaxf(0.f, accB[r]));
  }
  __syncthreads();   // (3) Gr, Wr ready
  // np = G^T W: 4 MFMAs per wave + transposed u16x4 stores + fused channel-stat atomics
  {
    int li = l & 15, lk = (l >> 4) * 8, lr = (l >> 4) * 4;
    s16x8 bfrag;
    #pragma unroll
    for (int j = 0; j < 8; ++j) bfrag[j] = (short)Wr[(lk + j)*72 + w*16 + li];
    int qb = (w*16 + li)*64 + lr;
    size_t obase = (size_t)point*4096 + qb;
    float* slot = slotC + (size_t)(point & (NSLOT-1)) * 8192;
    #pragma unroll
    for (int it = 0; it < 4; ++it){
      s16x8 afrag;
      #pragma unroll
      for (int j = 0; j < 8; ++j) afrag[j] = (short)Gr[(lk + j)*72 + it*16 + li];
      f32x4 z = {0.f, 0.f, 0.f, 0.f};
      f32x4 d = __builtin_amdgcn_mfma_f32_16x16x32_bf16(afrag, bfrag, z, 0, 0, 0);
      u16x4 st;
      st[0] = f2b(d[0]); st[1] = f2b(d[1]); st[2] = f2b(d[2]); st[3] = f2b(d[3]);
      *(u16x4*)(npw + obase + it*16) = st;
      #pragma unroll
      for (int r = 0; r < 4; ++r){
        atomicAdd(&slot[qb + it*16 + r], d[r]);
        atomicAdd(&slot[4096 + qb + it*16 + r], d[r]*d[r]);
      }
    }
  }
}

// ---------------- k_finC: reduce NSLOT slot copies + finalize (position space; gc/bc permuted) ----------------
__global__ __launch_bounds__(256) void k_finC(const float* slotC, const float* gc, const float* bc,
                                              float* AC, float* DC){
  int qpos = blockIdx.x * 256 + threadIdx.x;
  float s = 0.f, q = 0.f;
  #pragma unroll 8
  for (int sl = 0; sl < NSLOT; ++sl){
    s += slotC[(size_t)sl * 8192 + qpos];
    q += slotC[(size_t)sl * 8192 + 4096 + qpos];
  }
  int ch = (qpos & 63)*64 + (qpos >> 6);
  float m = s * (1.f/16384.f);
  float v = q * (1.f/16384.f) - m*m;
  float a = gc[ch] * rsqrtf(v + EPSF);
  AC[qpos] = a; DC[qpos] = bc[ch] - m*a;
}

// ---------------- k_linear ----------------
__global__ __launch_bounds__(256) void k_linear(const u16* npw, const float* AC, const float* DC,
                                                const u16* lwbt, const float* lb, float* yw,
                                                float* PL){
  __shared__ u16 Al[32*72];
  __shared__ u16 Bl[64*72];
  __shared__ float cps[64], cpq[64];
  int t = threadIdx.x;
  int w = t >> 6, l = t & 63;
  int rowbase = blockIdx.x * 32;
  int mt = w & 1, np2 = w >> 1;
  f32x4 acc0 = {0.f,0.f,0.f,0.f}, acc1 = acc0;
  for (int kb = 0; kb < 4096; kb += 64){
    __syncthreads();
    {
      int r = t >> 3, c8 = t & 7;
      int kk = kb + c8*8;
      u16x8 u = *(const u16x8*)(npw + (size_t)(rowbase + r)*4096 + kk);
      f32x4 alo = *(const f32x4*)(AC + kk), ahi = *(const f32x4*)(AC + kk + 4);
      f32x4 dlo = *(const f32x4*)(DC + kk), dhi = *(const f32x4*)(DC + kk + 4);
      u16x8 o;
      o[0] = f2b(fmaxf(0.f, alo.x*bf(u[0]) + dlo.x));
      o[1] = f2b(fmaxf(0.f, alo.y*bf(u[1]) + dlo.y));
      o[2] = f2b(fmaxf(0.f, alo.z*bf(u[2]) + dlo.z));
      o[3] = f2b(fmaxf(0.f, alo.w*bf(u[3]) + dlo.w));
      o[4] = f2b(fmaxf(0.f, ahi.x*bf(u[4]) + dhi.x));
      o[5] = f2b(fmaxf(0.f, ahi.y*bf(u[5]) + dhi.y));
      o[6] = f2b(fmaxf(0.f, ahi.z*bf(u[6]) + dhi.z));
      o[7] = f2b(fmaxf(0.f, ahi.w*bf(u[7]) + dhi.w));
      *(u16x8*)&Al[r*72 + c8*8] = o;
    }
    #pragma unroll
    for (int jj = 0; jj < 2; ++jj){
      int n = (t >> 3) + jj*32, c8 = t & 7;
      u16x8 u = *(const u16x8*)(lwbt + (size_t)n*4096 + kb + c8*8);
      *(u16x8*)&Bl[n*72 + c8*8] = u;
    }
    __syncthreads();
    #pragma unroll
    for (int ks = 0; ks < 2; ++ks){
      s16x8 af  = *(const s16x8*)&Al[(mt*16 + (l & 15))*72 + ks*32 + (l >> 4)*8];
      s16x8 bf0 = *(const s16x8*)&Bl[((np2*2    )*16 + (l & 15))*72 + ks*32 + (l >> 4)*8];
      s16x8 bf1 = *(const s16x8*)&Bl[((np2*2 + 1)*16 + (l & 15))*72 + ks*32 + (l >> 4)*8];
      acc0 = __builtin_amdgcn_mfma_f32_16x16x32_bf16(af, bf0, acc0, 0, 0, 0);
      acc1 = __builtin_amdgcn_mfma_f32_16x16x32_bf16(af, bf1, acc1, 0, 0, 0);
    }
  }
  int col0 = np2*32 + (l & 15), col1 = col0 + 16;
  float lb0 = lb[col0], lb1 = lb[col1];
  float s0 = 0.f, q0 = 0.f, s1 = 0.f, q1 = 0.f;
  if (t < 64){ cps[t] = 0.f; cpq[t] = 0.f; }
  __syncthreads();
  #pragma unroll
  for (int r = 0; r < 4; ++r){
    int row = rowbase + mt*16 + (l >> 4)*4 + r;
    float y0 = acc0[r] + lb0;
    float y1 = acc1[r] + lb1;
    yw[(size_t)row*64 + col0] = y0;
    yw[(size_t)row*64 + col1] = y1;
    s0 += y0; q0 += y0*y0; s1 += y1; q1 += y1*y1;
  }
  atomicAdd(&cps[col0], s0); atomicAdd(&cpq[col0], q0);
  atomicAdd(&cps[col1], s1); atomicAdd(&cpq[col1], q1);
  __syncthreads();
  if (t < 64){
    PL[blockIdx.x*128 + t]      = cps[t];
    PL[blockIdx.x*128 + 64 + t] = cpq[t];
  }
}

// ---------------- k_redF ----------------
__global__ __launch_bounds__(128) void k_redF(const float* PL, float* SL){
  int t = threadIdx.x;
  float s = 0.f;
  for (int b = 0; b < 512; ++b) s += PL[b*128 + t];
  SL[t] = s;
}

// ---------------- k_final ----------------
__global__ __launch_bounds__(256) void k_final(const float* yw, const float* SL,
                                               const float* gl, const float* bl, float* out){
  int e = (blockIdx.x * 256 + threadIdx.x) * 4;
  int o = e & 63;
  f32x4 y = *(const f32x4*)(yw + e);
  f32x4 r;
  #pragma unroll
  for (int j = 0; j < 4; ++j){
    float m = SL[o+j] * (1.f/16384.f);
    float v = SL[64+o+j] * (1.f/16384.f) - m*m;
    float a = gl[o+j] * rsqrtf(v + EPSF);
    float d = bl[o+j] - m*a;
    r[j] = fmaxf(0.f, a*y[j] + d);
  }
  *(f32x4*)(out + 49152 + e) = r;
}

extern "C" void kernel_launch(void* const* d_in, const int* in_sizes, int n_in,
                              void* d_out, int out_size, void* d_ws, size_t ws_size,
                              hipStream_t stream){
  (void)in_sizes; (void)n_in; (void)out_size; (void)ws_size;
  const float* xyz    = (const float*)d_in[0];
  const float* points = (const float*)d_in[1];
  const float* lc     = (const float*)d_in[2];
  const int*   nbrl   = (const int*)d_in[3];
  const int*   didx   = (const int*)d_in[4];
  const float* w0 = (const float*)d_in[5];
  const float* b0 = (const float*)d_in[6];
  const float* g0 = (const float*)d_in[7];
  const float* be0= (const float*)d_in[8];
  const float* w1 = (const float*)d_in[9];
  const float* b1 = (const float*)d_in[10];
  const float* g1 = (const float*)d_in[11];
  const float* be1= (const float*)d_in[12];
  const float* w2 = (const float*)d_in[13];
  const float* b2 = (const float*)d_in[14];
  const float* g2 = (const float*)d_in[15];
  const float* be2= (const float*)d_in[16];
  const float* gc = (const float*)d_in[17];
  const float* bc = (const float*)d_in[18];
  const float* lw = (const float*)d_in[19];
  const float* lb = (const float*)d_in[20];
  const float* gl = (const float*)d_in[21];
  const float* bl = (const float*)d_in[22];
  float* out = (float*)d_out;
  char* ws = (char*)d_ws;

  float* F   = (float*)ws;           // 1536
  float* SL  = F + 1536;             // 128
  float* AC  = SL + 128;             // 4096
  float* DC  = AC + 4096;            // 4096
  float* PA  = DC + 4096;            // 32768
  float* PB1 = PA + 32768;           // 139264
  float* PB2 = PB1 + 139264;         // 139264
  float* PL  = PB2 + 139264;         // 65536
  u16*  w1Bg = (u16*)(PL + 65536);   // 512 u16
  u16*  w2Bg = w1Bg + 512;           // 2048 u16
  float* slotC = (float*)(ws + 4194304);                      // NSLOT*8192 f32 = 2 MB
  u16*  npw  = (u16*)(ws + 4194304 + 8388608);                // 128 MB bf16 (transposed)
  float* yw  = (float*)(ws + 4194304 + 8388608 + 134217728);  // 4 MB f32
  u16*  lwbt = (u16*)(ws + 4194304 + 8388608 + 134217728 + 4194304); // 512 KB (permuted)

  hipMemsetAsync(slotC, 0, NSLOT * 8192 * sizeof(float), stream);
  k_init  <<<128,   256, 0, stream>>>(xyz, didx, out, lw, lwbt);
  k_stat0 <<<512,   256, 0, stream>>>(lc, PA);
  k_red0  <<<1,     256, 0, stream>>>(PA, w0, b0, g0, be0, F);
  k_statG<false><<<SGBLK, 256, 0, stream>>>(lc, F, PB1);
  k_red1  <<<1,     256, 0, stream>>>(PB1, w1, b1, g1, be1, F, w1Bg);
  k_statG<true> <<<SGBLK, 256, 0, stream>>>(lc, F, PB2);
  k_red2  <<<1,     256, 0, stream>>>(PB2, w2, b2, g2, be2, F, w2Bg);
  k_main  <<<16384, 256, 0, stream>>>(lc, nbrl, points, xyz, F, w1Bg, w2Bg, npw, slotC);
  k_finC  <<<16,    256, 0, stream>>>(slotC, gc, bc, AC, DC);
  k_linear<<<512,   256, 0, stream>>>(npw, AC, DC, lwbt, lb, yw, PL);
  k_redF  <<<1,     128, 0, stream>>>(PL, SL);
  k_final <<<1024,  256, 0, stream>>>(yw, SL, gl, bl, out);
}

// Round 16
// 273.409 us; speedup vs baseline: 6.4549x; 6.4549x over previous
//
#include <hip/hip_runtime.h>
#include <hip/hip_bf16.h>

#define BB 16
#define NN 4096
#define NPOINTS 1024
#define KK 32
#define NPTS (BB*NPOINTS)        // 16384
#define NWN  (BB*NPOINTS*KK)     // 524288
#define EPSF 1e-5f
#define SGBLK 512
#define SGIT  4

typedef unsigned short u16;
typedef u16  u16x8 __attribute__((ext_vector_type(8)));
typedef u16  u16x4 __attribute__((ext_vector_type(4)));
typedef short s16x8 __attribute__((ext_vector_type(8)));
typedef float f32x4 __attribute__((ext_vector_type(4)));
typedef float f32x4u __attribute__((ext_vector_type(4), aligned(4)));

__device__ __forceinline__ float bf(u16 u){
  union { unsigned int i; float f; } v; v.i = ((unsigned int)u) << 16; return v.f;
}
__device__ __forceinline__ u16 f2b(float f){
  __hip_bfloat16 h = __float2bfloat16(f);
  union { __hip_bfloat16 hh; u16 u; } v; v.hh = h; return v.u;
}

// F layout (folded weights): [0..47] w0f, [48..63] b0f, [64..319] w1f,
// [320..335] b1f, [336..1359] w2f, [1360..1423] b2f
// npw: transposed position space q = o*64 + i  (original channel ch = i*64 + o)
// w1Bg[64][8], w2Bg[4][64][8]: per-lane bf16 MFMA B-fragments (ic zero-padded to 32)
// NOTE (round 15 lesson): device-scope atomics bypass L2 on MI355X (XCD non-coherence)
// -> every atomicAdd is an HBM round-trip. Keep stats as a streaming pass (k_statC).

// ---------------- k_init ----------------
__global__ __launch_bounds__(256) void k_init(const float* xyz, const int* didx, float* out,
                                              const float* lw, u16* lwbt){
  int t = threadIdx.x;
  if (blockIdx.x < 64){
    int p = blockIdx.x * 256 + t;
    int b = p >> 10;
    int idx = didx[p];
    const float* src = xyz + ((size_t)(b * NN + idx)) * 3;
    float* dst = out + (size_t)p * 3;
    dst[0] = src[0]; dst[1] = src[1]; dst[2] = src[2];
  } else {
    __shared__ float T[64][65];
    int ib = blockIdx.x - 64;
    int kb = ib * 64;
    {
      int k = t >> 2, c4 = t & 3;
      #pragma unroll
      for (int j = 0; j < 4; ++j)
        *(f32x4*)&T[k][c4*16 + j*4] = *(const f32x4*)(lw + (size_t)(kb + k)*64 + c4*16 + j*4);
    }
    __syncthreads();
    {
      int n = t >> 2, k4 = t & 3;
      #pragma unroll
      for (int j = 0; j < 16; ++j){
        int k = k4*16 + j;
        lwbt[(size_t)n*4096 + k*64 + ib] = f2b(T[k][n]);
      }
    }
  }
}

// ---------------- k_stat0 ----------------
__global__ __launch_bounds__(256) void k_stat0(const float* lc, float* PA){
  int t = threadIdx.x;
  float a[9];
  #pragma unroll
  for (int r = 0; r < 9; ++r) a[r] = 0.f;
  size_t base = (size_t)blockIdx.x * 1024 + t;
  for (int ip = 0; ip < 4; ++ip){
    size_t p = base + (size_t)ip * 256;
    float x0 = lc[p*3], x1 = lc[p*3+1], x2 = lc[p*3+2];
    a[0]+=x0; a[1]+=x1; a[2]+=x2;
    a[3]+=x0*x0; a[4]+=x0*x1; a[5]+=x0*x2;
    a[6]+=x1*x1; a[7]+=x1*x2; a[8]+=x2*x2;
  }
  #pragma unroll
  for (int m = 1; m < 64; m <<= 1){
    #pragma unroll
    for (int r = 0; r < 9; ++r) a[r] += __shfl_xor(a[r], m);
  }
  if ((t & 63) == 0){
    float* dst = PA + (size_t)(blockIdx.x*4 + (t>>6)) * 16;
    f32x4 v0 = {a[0],a[1],a[2],a[3]}, v1 = {a[4],a[5],a[6],a[7]}, v2 = {a[8],0.f,0.f,0.f};
    *(f32x4*)dst = v0; *(f32x4*)(dst+4) = v1; *(f32x4*)(dst+8) = v2;
  }
}

// ---------------- k_red0 ----------------
__global__ __launch_bounds__(256) void k_red0(const float* PA, const float* w0, const float* b0,
                                              const float* g0, const float* be0, float* F){
  __shared__ float ms[12];
  __shared__ float a0sh[16];
  int t = threadIdx.x;
  if (t < 12){
    float s0=0,s1=0,s2=0,s3=0;
    const float* p = PA + t;
    for (int r = 0; r < 2048; r += 4){
      s0 += p[(size_t)(r+0)*16]; s1 += p[(size_t)(r+1)*16];
      s2 += p[(size_t)(r+2)*16]; s3 += p[(size_t)(r+3)*16];
    }
    ms[t] = (s0+s1)+(s2+s3);
  }
  __syncthreads();
  if (t < 16){
    float wx = w0[t*3], wy = w0[t*3+1], wz = w0[t*3+2], bb = b0[t];
    float lin = wx*ms[0] + wy*ms[1] + wz*ms[2];
    float quad = wx*wx*ms[3] + wy*wy*ms[6] + wz*wz*ms[8]
               + 2.f*(wx*wy*ms[4] + wx*wz*ms[5] + wy*wz*ms[7]);
    float S = lin + (float)NWN * bb;
    float Q = quad + 2.f*bb*lin + (float)NWN*bb*bb;
    float m = S * (1.f/NWN);
    float v = Q * (1.f/NWN) - m*m;
    float a = g0[t] * rsqrtf(v + EPSF);
    float d = be0[t] - m*a;
    a0sh[t] = a;
    F[48+t] = a*bb + d;
  }
  __syncthreads();
  if (t < 48) F[t] = a0sh[t/3] * w0[t];
}

// ---------------- k_statG ----------------
template<bool L2>
__global__ __launch_bounds__(256) void k_statG(const float* lc, const float* F, float* PB){
  __shared__ f32x4 w0p[16];
  __shared__ float w1s[256], b1fs[16];
  __shared__ __align__(16) u16 Ht[4][16*72];
  __shared__ float GS[4][16][17];
  __shared__ float SHs[4][16];
  int t = threadIdx.x;
  int w = t >> 6, l = t & 63;
  if (t < 16){
    f32x4 wv = {F[t*3], F[t*3+1], F[t*3+2], F[48+t]};
    w0p[t] = wv;
    if (L2) b1fs[t] = F[320+t];
  }
  if (L2) w1s[t] = F[64+t];
  __syncthreads();
  f32x4 acc = {0.f,0.f,0.f,0.f};
  float sh[16];
  #pragma unroll
  for (int r = 0; r < 16; ++r) sh[r] = 0.f;
  u16* Hw = &Ht[w][0];
  for (int it = 0; it < SGIT; ++it){
    size_t p = (size_t)blockIdx.x * (SGIT*256) + (size_t)it*256 + w*64 + l;
    float x0 = lc[p*3], x1 = lc[p*3+1], x2 = lc[p*3+2];
    float h[16];
    #pragma unroll
    for (int oc = 0; oc < 16; ++oc){
      f32x4 wv = w0p[oc];
      h[oc] = fmaxf(0.f, wv.x*x0 + wv.y*x1 + wv.z*x2 + wv.w);
    }
    if (L2){
      float h1[16];
      #pragma unroll
      for (int oc = 0; oc < 16; ++oc){
        const f32x4* wr = (const f32x4*)&w1s[oc*16];
        f32x4 wa = wr[0], wb = wr[1], wc = wr[2], wd = wr[3];
        float y = b1fs[oc];
        y += wa.x*h[0]  + wa.y*h[1]  + wa.z*h[2]  + wa.w*h[3];
        y += wb.x*h[4]  + wb.y*h[5]  + wb.z*h[6]  + wb.w*h[7];
        y += wc.x*h[8]  + wc.y*h[9]  + wc.z*h[10] + wc.w*h[11];
        y += wd.x*h[12] + wd.y*h[13] + wd.z*h[14] + wd.w*h[15];
        h1[oc] = fmaxf(0.f, y);
      }
      #pragma unroll
      for (int oc = 0; oc < 16; ++oc) h[oc] = h1[oc];
    }
    #pragma unroll
    for (int oc = 0; oc < 16; ++oc) sh[oc] += h[oc];
    #pragma unroll
    for (int c = 0; c < 16; ++c) Hw[c*72 + l] = f2b(h[c]);
    __syncthreads();
    #pragma unroll
    for (int tt = 0; tt < 2; ++tt){
      s16x8 af = *(const s16x8*)&Hw[(l & 15)*72 + tt*32 + (l >> 4)*8];
      acc = __builtin_amdgcn_mfma_f32_16x16x32_bf16(af, af, acc, 0, 0, 0);
    }
    __syncthreads();
  }
  #pragma unroll
  for (int r = 0; r < 4; ++r)
    GS[w][(l>>4)*4 + r][l & 15] = acc[r];
  #pragma unroll
  for (int m = 1; m < 64; m <<= 1){
    #pragma unroll
    for (int r = 0; r < 16; ++r) sh[r] += __shfl_xor(sh[r], m);
  }
  if (l == 0){
    #pragma unroll
    for (int r = 0; r < 16; ++r) SHs[w][r] = sh[r];
  }
  __syncthreads();
  {
    int i = t >> 4, j = t & 15;
    float g = GS[0][i][j] + GS[1][i][j] + GS[2][i][j] + GS[3][i][j];
    PB[(size_t)blockIdx.x*272 + t] = g;
    if (t < 16)
      PB[(size_t)blockIdx.x*272 + 256 + t] = SHs[0][t]+SHs[1][t]+SHs[2][t]+SHs[3][t];
  }
}

// ---------------- k_red1 ----------------
__global__ __launch_bounds__(256) void k_red1(const float* PB, const float* w1, const float* b1,
                                              const float* g1, const float* be1, float* F,
                                              u16* w1Bg){
  __shared__ float red[272];
  __shared__ float a1sh[16];
  int t = threadIdx.x;
  for (int e = t; e < 272; e += 256){
    float s = 0.f;
    for (int r = 0; r < SGBLK; ++r) s += PB[(size_t)r*272 + e];
    red[e] = s;
  }
  __syncthreads();
  if (t < 16){
    float wv[16];
    #pragma unroll
    for (int ic = 0; ic < 16; ++ic) wv[ic] = w1[t*16+ic];
    float lin = 0.f;
    #pragma unroll
    for (int ic = 0; ic < 16; ++ic) lin += wv[ic]*red[256+ic];
    float quad = 0.f;
    for (int i = 0; i < 16; ++i){
      float ri = 0.f;
      #pragma unroll
      for (int j = 0; j < 16; ++j) ri += wv[j]*red[i*16+j];
      quad += wv[i]*ri;
    }
    float bb = b1[t];
    float S = lin + (float)NWN * bb;
    float Q = quad + 2.f*bb*lin + (float)NWN*bb*bb;
    float m = S * (1.f/NWN);
    float v = Q * (1.f/NWN) - m*m;
    float a = g1[t] * rsqrtf(v + EPSF);
    float d = be1[t] - m*a;
    a1sh[t] = a;
    F[320+t] = a*bb + d;
  }
  __syncthreads();
  F[64 + t] = a1sh[t >> 4] * w1[t];
  if (t < 64){
    int oc = t & 15, icb = (t >> 4) * 8;
    u16x8 fr;
    #pragma unroll
    for (int j = 0; j < 8; ++j){
      int ic = icb + j;
      fr[j] = (ic < 16) ? f2b(a1sh[oc] * w1[oc*16 + ic]) : (u16)0;
    }
    *(u16x8*)&w1Bg[t*8] = fr;
  }
}

// ---------------- k_red2 ----------------
__global__ __launch_bounds__(256) void k_red2(const float* PB, const float* w2, const float* b2,
                                              const float* g2, const float* be2, float* F,
                                              u16* w2Bg){
  __shared__ float red[272];
  __shared__ float a2sh[64];
  int t = threadIdx.x;
  for (int e = t; e < 272; e += 256){
    float s = 0.f;
    for (int r = 0; r < SGBLK; ++r) s += PB[(size_t)r*272 + e];
    red[e] = s;
  }
  __syncthreads();
  if (t < 64){
    float wv[16];
    #pragma unroll
    for (int ic = 0; ic < 16; ++ic) wv[ic] = w2[t*16+ic];
    float lin = 0.f;
    #pragma unroll
    for (int ic = 0; ic < 16; ++ic) lin += wv[ic]*red[256+ic];
    float quad = 0.f;
    for (int i = 0; i < 16; ++i){
      float ri = 0.f;
      #pragma unroll
      for (int j = 0; j < 16; ++j) ri += wv[j]*red[i*16+j];
      quad += wv[i]*ri;
    }
    float bb = b2[t];
    float S = lin + (float)NWN * bb;
    float Q = quad + 2.f*bb*lin + (float)NWN*bb*bb;
    float m = S * (1.f/NWN);
    float v = Q * (1.f/NWN) - m*m;
    float a = g2[t] * rsqrtf(v + EPSF);
    float d = be2[t] - m*a;
    a2sh[t] = a;
    F[1360+t] = a*bb + d;
  }
  __syncthreads();
  for (int i = t; i < 1024; i += 256) F[336+i] = a2sh[i >> 4] * w2[i];
  {
    int ot = t >> 6, lane = t & 63;
    int oc = ot*16 + (lane & 15), icb = ((lane >> 4)) * 8;
    u16x8 fr;
    #pragma unroll
    for (int j = 0; j < 8; ++j){
      int ic = icb + j;
      fr[j] = (ic < 16) ? f2b(a2sh[oc] * w2[oc*16 + ic]) : (u16)0;
    }
    *(u16x8*)&w2Bg[t*8] = fr;
  }
}

// ---------------- K5: one point per block — MFMA WeightNet + MFMA matmul (K-major Gr/Wr) ----------------
__global__ __launch_bounds__(256) void k_main(const float* lcg, const int* nbrg,
    const float* points, const float* xyz, const float* F,
    const u16* w1Bg, const u16* w2Bg,
    u16* npw){
  __shared__ __align__(16) u16 Gr[64*40];           // bf16 K-major: Gr[i][k], stride 40
  __shared__ __align__(16) u16 Wr[64*40];           // bf16 K-major: Wr[o][k], stride 40
  __shared__ __align__(16) u16 H0bf[32*40];         // bf16 [k][ic], ic zero-padded to 32
  __shared__ __align__(16) u16 H1bf[32*40];
  __shared__ float w0c[48], b0c[16];
  int t = threadIdx.x;
  int w = t >> 6, l = t & 63;
  int point = blockIdx.x;
  int bb = point >> 10;
  // early frag loads (registers, L2-hot)
  s16x8 w1B = *(const s16x8*)&w1Bg[l*8];
  int otA = (w & 1)*2, otB = otA + 1;
  s16x8 w2BA = *(const s16x8*)&w2Bg[(otA*64 + l)*8];
  s16x8 w2BB = *(const s16x8*)&w2Bg[(otB*64 + l)*8];
  float b1f = F[320 + (l & 15)];
  float b2fA = F[1360 + otA*16 + (l & 15)];
  float b2fB = F[1360 + otB*16 + (l & 15)];
  if (t < 48) w0c[t] = F[t];
  if (t < 16) b0c[t] = F[48+t];
  // zero-pad ic 16..31 of H0bf and H1bf
  {
    int k = t >> 3, c = 16 + (t & 7)*2;
    *(unsigned int*)&H0bf[k*40 + c] = 0u;
    *(unsigned int*)&H1bf[k*40 + c] = 0u;
  }
  // gather -> Gr K-major (8 scalar u16 writes, bank-spread stride 80B)
  {
    int kg = w*8 + (l >> 3), c8 = l & 7;
    int n = nbrg[(size_t)point*32 + kg];
    const float* prow = points + (size_t)(bb * NN + n) * 61;
    float v[8];
    if (c8 < 7){
      f32x4 lo = *(const f32x4u*)(prow + c8*8);
      f32x4 hi = *(const f32x4u*)(prow + c8*8 + 4);
      v[0]=lo.x; v[1]=lo.y; v[2]=lo.z; v[3]=lo.w;
      v[4]=hi.x; v[5]=hi.y; v[6]=hi.z; v[7]=hi.w;
    } else {
      const float* xr = xyz + (size_t)(bb * NN + n) * 3;
      f32x4 lo = *(const f32x4u*)(prow + 56);
      v[0]=lo.x; v[1]=lo.y; v[2]=lo.z; v[3]=lo.w;
      v[4]=prow[60];
      v[5]=xr[0]; v[6]=xr[1]; v[7]=xr[2];
    }
    #pragma unroll
    for (int j = 0; j < 8; ++j)
      Gr[(c8*8 + j)*40 + kg] = f2b(v[j]);
  }
  __syncthreads();   // (0) w0c/b0c staged before any H0 read
  // H0 -> H0bf
  {
    int k = t >> 3, oc0 = (t & 7)*2;
    const float* xp = lcg + (size_t)point*96 + k*3;
    float x0 = xp[0], x1 = xp[1], x2 = xp[2];
    #pragma unroll
    for (int e = 0; e < 2; ++e){
      int oc = oc0 + e;
      float y = w0c[oc*3]*x0 + w0c[oc*3+1]*x1 + w0c[oc*3+2]*x2 + b0c[oc];
      H0bf[k*40 + oc] = f2b(fmaxf(0.f, y));
    }
  }
  __syncthreads();   // (1) H0bf ready
  // H1 = relu(H0 · w1f^T + b1f): 2 MFMAs, waves 0-1
  if (w < 2){
    int kt = w;
    s16x8 af = *(const s16x8*)&H0bf[(kt*16 + (l & 15))*40 + (l >> 4)*8];
    f32x4 acc = {b1f, b1f, b1f, b1f};
    acc = __builtin_amdgcn_mfma_f32_16x16x32_bf16(af, w1B, acc, 0, 0, 0);
    #pragma unroll
    for (int r = 0; r < 4; ++r)
      H1bf[(kt*16 + (l >> 4)*4 + r)*40 + (l & 15)] = f2b(fmaxf(0.f, acc[r]));
  }
  __syncthreads();   // (2) H1bf ready
  // W = relu(H1 · w2f^T + b2f): 8 MFMAs across 4 waves, K-major u16x4 writes
  {
    int kt = w >> 1;
    s16x8 af = *(const s16x8*)&H1bf[(kt*16 + (l & 15))*40 + (l >> 4)*8];
    int kbase = kt*16 + (l >> 4)*4;
    f32x4 accA = {b2fA, b2fA, b2fA, b2fA};
    accA = __builtin_amdgcn_mfma_f32_16x16x32_bf16(af, w2BA, accA, 0, 0, 0);
    u16x4 sA;
    sA[0]=f2b(fmaxf(0.f,accA[0])); sA[1]=f2b(fmaxf(0.f,accA[1]));
    sA[2]=f2b(fmaxf(0.f,accA[2])); sA[3]=f2b(fmaxf(0.f,accA[3]));
    *(u16x4*)&Wr[(otA*16 + (l & 15))*40 + kbase] = sA;
    f32x4 accB = {b2fB, b2fB, b2fB, b2fB};
    accB = __builtin_amdgcn_mfma_f32_16x16x32_bf16(af, w2BB, accB, 0, 0, 0);
    u16x4 sB;
    sB[0]=f2b(fmaxf(0.f,accB[0])); sB[1]=f2b(fmaxf(0.f,accB[1]));
    sB[2]=f2b(fmaxf(0.f,accB[2])); sB[3]=f2b(fmaxf(0.f,accB[3]));
    *(u16x4*)&Wr[(otB*16 + (l & 15))*40 + kbase] = sB;
  }
  __syncthreads();   // (3) Gr, Wr ready
  // np = G^T W: 4 MFMAs per wave, b128 frag reads, transposed u16x4 stores
  {
    int li = l & 15, lk = (l >> 4) * 8, lr = (l >> 4) * 4;
    s16x8 bfrag = *(const s16x8*)&Wr[(w*16 + li)*40 + lk];
    size_t obase = (size_t)point*4096 + (size_t)(w*16 + li)*64 + lr;
    #pragma unroll
    for (int it = 0; it < 4; ++it){
      s16x8 afrag = *(const s16x8*)&Gr[(it*16 + li)*40 + lk];
      f32x4 z = {0.f, 0.f, 0.f, 0.f};
      f32x4 d = __builtin_amdgcn_mfma_f32_16x16x32_bf16(afrag, bfrag, z, 0, 0, 0);
      u16x4 st;
      st[0] = f2b(d[0]); st[1] = f2b(d[1]); st[2] = f2b(d[2]); st[3] = f2b(d[3]);
      *(u16x4*)(npw + obase + it*16) = st;
    }
  }
}

// ---------------- k_statC: position-space stats from npw (streaming, coalesced) ----------------
__global__ __launch_bounds__(256) void k_statC(const u16* npw, float* PC){
  int t = threadIdx.x;
  float s[16], q[16];
  #pragma unroll
  for (int j = 0; j < 16; ++j){ s[j] = 0.f; q[j] = 0.f; }
  size_t rowbase = (size_t)blockIdx.x * 64;
  for (int p = 0; p < 64; ++p){
    const u16* row = npw + (rowbase + p) * 4096 + t * 16;
    u16x8 a = *(const u16x8*)row;
    u16x8 b = *(const u16x8*)(row + 8);
    #pragma unroll
    for (int j = 0; j < 8; ++j){ float v = bf(a[j]); s[j]   += v; q[j]   += v*v; }
    #pragma unroll
    for (int j = 0; j < 8; ++j){ float v = bf(b[j]); s[8+j] += v; q[8+j] += v*v; }
  }
  float* dst = PC + (size_t)blockIdx.x * 8192 + t * 16;
  #pragma unroll
  for (int j = 0; j < 16; ++j){ dst[j] = s[j]; dst[4096 + j] = q[j]; }
}

// ---------------- k_finC (position space; gc/bc permuted) ----------------
__global__ __launch_bounds__(256) void k_finC(const float* PC, const float* gc, const float* bc,
                                              float* AC, float* DC){
  int qpos = blockIdx.x * 256 + threadIdx.x;
  float s = 0.f, q = 0.f;
  for (int r = 0; r < 256; ++r){
    s += PC[(size_t)r * 8192 + qpos];
    q += PC[(size_t)r * 8192 + 4096 + qpos];
  }
  int ch = (qpos & 63)*64 + (qpos >> 6);
  float m = s * (1.f/16384.f);
  float v = q * (1.f/16384.f) - m*m;
  float a = gc[ch] * rsqrtf(v + EPSF);
  AC[qpos] = a; DC[qpos] = bc[ch] - m*a;
}

// ---------------- k_linear ----------------
__global__ __launch_bounds__(256) void k_linear(const u16* npw, const float* AC, const float* DC,
                                                const u16* lwbt, const float* lb, float* yw,
                                                float* PL){
  __shared__ u16 Al[32*72];
  __shared__ u16 Bl[64*72];
  __shared__ float cps[64], cpq[64];
  int t = threadIdx.x;
  int w = t >> 6, l = t & 63;
  int rowbase = blockIdx.x * 32;
  int mt = w & 1, np2 = w >> 1;
  f32x4 acc0 = {0.f,0.f,0.f,0.f}, acc1 = acc0;
  for (int kb = 0; kb < 4096; kb += 64){
    __syncthreads();
    {
      int r = t >> 3, c8 = t & 7;
      int kk = kb + c8*8;
      u16x8 u = *(const u16x8*)(npw + (size_t)(rowbase + r)*4096 + kk);
      f32x4 alo = *(const f32x4*)(AC + kk), ahi = *(const f32x4*)(AC + kk + 4);
      f32x4 dlo = *(const f32x4*)(DC + kk), dhi = *(const f32x4*)(DC + kk + 4);
      u16x8 o;
      o[0] = f2b(fmaxf(0.f, alo.x*bf(u[0]) + dlo.x));
      o[1] = f2b(fmaxf(0.f, alo.y*bf(u[1]) + dlo.y));
      o[2] = f2b(fmaxf(0.f, alo.z*bf(u[2]) + dlo.z));
      o[3] = f2b(fmaxf(0.f, alo.w*bf(u[3]) + dlo.w));
      o[4] = f2b(fmaxf(0.f, ahi.x*bf(u[4]) + dhi.x));
      o[5] = f2b(fmaxf(0.f, ahi.y*bf(u[5]) + dhi.y));
      o[6] = f2b(fmaxf(0.f, ahi.z*bf(u[6]) + dhi.z));
      o[7] = f2b(fmaxf(0.f, ahi.w*bf(u[7]) + dhi.w));
      *(u16x8*)&Al[r*72 + c8*8] = o;
    }
    #pragma unroll
    for (int jj = 0; jj < 2; ++jj){
      int n = (t >> 3) + jj*32, c8 = t & 7;
      u16x8 u = *(const u16x8*)(lwbt + (size_t)n*4096 + kb + c8*8);
      *(u16x8*)&Bl[n*72 + c8*8] = u;
    }
    __syncthreads();
    #pragma unroll
    for (int ks = 0; ks < 2; ++ks){
      s16x8 af  = *(const s16x8*)&Al[(mt*16 + (l & 15))*72 + ks*32 + (l >> 4)*8];
      s16x8 bf0 = *(const s16x8*)&Bl[((np2*2    )*16 + (l & 15))*72 + ks*32 + (l >> 4)*8];
      s16x8 bf1 = *(const s16x8*)&Bl[((np2*2 + 1)*16 + (l & 15))*72 + ks*32 + (l >> 4)*8];
      acc0 = __builtin_amdgcn_mfma_f32_16x16x32_bf16(af, bf0, acc0, 0, 0, 0);
      acc1 = __builtin_amdgcn_mfma_f32_16x16x32_bf16(af, bf1, acc1, 0, 0, 0);
    }
  }
  int col0 = np2*32 + (l & 15), col1 = col0 + 16;
  float lb0 = lb[col0], lb1 = lb[col1];
  float s0 = 0.f, q0 = 0.f, s1 = 0.f, q1 = 0.f;
  if (t < 64){ cps[t] = 0.f; cpq[t] = 0.f; }
  __syncthreads();
  #pragma unroll
  for (int r = 0; r < 4; ++r){
    int row = rowbase + mt*16 + (l >> 4)*4 + r;
    float y0 = acc0[r] + lb0;
    float y1 = acc1[r] + lb1;
    yw[(size_t)row*64 + col0] = y0;
    yw[(size_t)row*64 + col1] = y1;
    s0 += y0; q0 += y0*y0; s1 += y1; q1 += y1*y1;
  }
  atomicAdd(&cps[col0], s0); atomicAdd(&cpq[col0], q0);
  atomicAdd(&cps[col1], s1); atomicAdd(&cpq[col1], q1);
  __syncthreads();
  if (t < 64){
    PL[blockIdx.x*128 + t]      = cps[t];
    PL[blockIdx.x*128 + 64 + t] = cpq[t];
  }
}

// ---------------- k_redF ----------------
__global__ __launch_bounds__(128) void k_redF(const float* PL, float* SL){
  int t = threadIdx.x;
  float s = 0.f;
  for (int b = 0; b < 512; ++b) s += PL[b*128 + t];
  SL[t] = s;
}

// ---------------- k_final ----------------
__global__ __launch_bounds__(256) void k_final(const float* yw, const float* SL,
                                               const float* gl, const float* bl, float* out){
  int e = (blockIdx.x * 256 + threadIdx.x) * 4;
  int o = e & 63;
  f32x4 y = *(const f32x4*)(yw + e);
  f32x4 r;
  #pragma unroll
  for (int j = 0; j < 4; ++j){
    float m = SL[o+j] * (1.f/16384.f);
    float v = SL[64+o+j] * (1.f/16384.f) - m*m;
    float a = gl[o+j] * rsqrtf(v + EPSF);
    float d = bl[o+j] - m*a;
    r[j] = fmaxf(0.f, a*y[j] + d);
  }
  *(f32x4*)(out + 49152 + e) = r;
}

extern "C" void kernel_launch(void* const* d_in, const int* in_sizes, int n_in,
                              void* d_out, int out_size, void* d_ws, size_t ws_size,
                              hipStream_t stream){
  (void)in_sizes; (void)n_in; (void)out_size; (void)ws_size;
  const float* xyz    = (const float*)d_in[0];
  const float* points = (const float*)d_in[1];
  const float* lc     = (const float*)d_in[2];
  const int*   nbrl   = (const int*)d_in[3];
  const int*   didx   = (const int*)d_in[4];
  const float* w0 = (const float*)d_in[5];
  const float* b0 = (const float*)d_in[6];
  const float* g0 = (const float*)d_in[7];
  const float* be0= (const float*)d_in[8];
  const float* w1 = (const float*)d_in[9];
  const float* b1 = (const float*)d_in[10];
  const float* g1 = (const float*)d_in[11];
  const float* be1= (const float*)d_in[12];
  const float* w2 = (const float*)d_in[13];
  const float* b2 = (const float*)d_in[14];
  const float* g2 = (const float*)d_in[15];
  const float* be2= (const float*)d_in[16];
  const float* gc = (const float*)d_in[17];
  const float* bc = (const float*)d_in[18];
  const float* lw = (const float*)d_in[19];
  const float* lb = (const float*)d_in[20];
  const float* gl = (const float*)d_in[21];
  const float* bl = (const float*)d_in[22];
  float* out = (float*)d_out;
  char* ws = (char*)d_ws;

  float* F   = (float*)ws;           // 1536
  float* SL  = F + 1536;             // 128
  float* AC  = SL + 128;             // 4096
  float* DC  = AC + 4096;            // 4096
  float* PA  = DC + 4096;            // 32768
  float* PB1 = PA + 32768;           // 139264
  float* PB2 = PB1 + 139264;         // 139264
  float* PL  = PB2 + 139264;         // 65536
  u16*  w1Bg = (u16*)(PL + 65536);   // 512 u16
  u16*  w2Bg = w1Bg + 512;           // 2048 u16
  float* PC  = (float*)(ws + 4194304);                        // 8 MB
  u16*  npw  = (u16*)(ws + 4194304 + 8388608);                // 128 MB bf16 (transposed)
  float* yw  = (float*)(ws + 4194304 + 8388608 + 134217728);  // 4 MB f32
  u16*  lwbt = (u16*)(ws + 4194304 + 8388608 + 134217728 + 4194304); // 512 KB (permuted)

  k_init  <<<128,   256, 0, stream>>>(xyz, didx, out, lw, lwbt);
  k_stat0 <<<512,   256, 0, stream>>>(lc, PA);
  k_red0  <<<1,     256, 0, stream>>>(PA, w0, b0, g0, be0, F);
  k_statG<false><<<SGBLK, 256, 0, stream>>>(lc, F, PB1);
  k_red1  <<<1,     256, 0, stream>>>(PB1, w1, b1, g1, be1, F, w1Bg);
  k_statG<true> <<<SGBLK, 256, 0, stream>>>(lc, F, PB2);
  k_red2  <<<1,     256, 0, stream>>>(PB2, w2, b2, g2, be2, F, w2Bg);
  k_main  <<<16384, 256, 0, stream>>>(lc, nbrl, points, xyz, F, w1Bg, w2Bg, npw);
  k_statC <<<256,   256, 0, stream>>>(npw, PC);
  k_finC  <<<16,    256, 0, stream>>>(PC, gc, bc, AC, DC);
  k_linear<<<512,   256, 0, stream>>>(npw, AC, DC, lwbt, lb, yw, PL);
  k_redF  <<<1,     128, 0, stream>>>(PL, SL);
  k_final <<<1024,  256, 0, stream>>>(yw, SL, gl, bl, out);
}

// Round 17
// 266.660 us; speedup vs baseline: 6.6183x; 1.0253x over previous
//
#include <hip/hip_runtime.h>
#include <hip/hip_bf16.h>

#define BB 16
#define NN 4096
#define NPOINTS 1024
#define KK 32
#define NPTS (BB*NPOINTS)        // 16384
#define NWN  (BB*NPOINTS*KK)     // 524288
#define EPSF 1e-5f
#define SGBLK 512
#define SGIT  4

typedef unsigned short u16;
typedef u16  u16x8 __attribute__((ext_vector_type(8)));
typedef u16  u16x4 __attribute__((ext_vector_type(4)));
typedef short s16x8 __attribute__((ext_vector_type(8)));
typedef float f32x4 __attribute__((ext_vector_type(4)));
typedef float f32x4u __attribute__((ext_vector_type(4), aligned(4)));

__device__ __forceinline__ float bf(u16 u){
  union { unsigned int i; float f; } v; v.i = ((unsigned int)u) << 16; return v.f;
}
__device__ __forceinline__ u16 f2b(float f){
  __hip_bfloat16 h = __float2bfloat16(f);
  union { __hip_bfloat16 hh; u16 u; } v; v.hh = h; return v.u;
}

// F layout (folded weights): [0..47] w0f, [48..63] b0f, [64..319] w1f,
// [320..335] b1f, [336..1359] w2f, [1360..1423] b2f
// npw: transposed position space q = o*64 + i  (original channel ch = i*64 + o)
// ptsw[B*N][64] bf16: pre-converted concat(points, xyz) rows (gather table)
// NOTE (round 15): device atomics bypass L2 on MI355X -> keep stats streaming.

// ---------------- k_init: newxyz (0..63) + lwbt (64..127) + ptsw build (128..639) ----------------
__global__ __launch_bounds__(256) void k_init(const float* xyz, const int* didx, float* out,
                                              const float* lw, u16* lwbt,
                                              const float* points, u16* ptsw){
  int t = threadIdx.x;
  if (blockIdx.x < 64){
    int p = blockIdx.x * 256 + t;
    int b = p >> 10;
    int idx = didx[p];
    const float* src = xyz + ((size_t)(b * NN + idx)) * 3;
    float* dst = out + (size_t)p * 3;
    dst[0] = src[0]; dst[1] = src[1]; dst[2] = src[2];
  } else if (blockIdx.x < 128){
    __shared__ float T[64][65];
    int ib = blockIdx.x - 64;
    int kb = ib * 64;
    {
      int k = t >> 2, c4 = t & 3;
      #pragma unroll
      for (int j = 0; j < 4; ++j)
        *(f32x4*)&T[k][c4*16 + j*4] = *(const f32x4*)(lw + (size_t)(kb + k)*64 + c4*16 + j*4);
    }
    __syncthreads();
    {
      int n = t >> 2, k4 = t & 3;
      #pragma unroll
      for (int j = 0; j < 16; ++j){
        int k = k4*16 + j;
        lwbt[(size_t)n*4096 + k*64 + ib] = f2b(T[k][n]);
      }
    }
  } else {
    // build ptsw: 512 blocks x 256 threads x 4 reps = 524288 u16x8 chunks
    int gid0 = (blockIdx.x - 128) * 256 + t;
    #pragma unroll
    for (int rep = 0; rep < 4; ++rep){
      int idx = gid0 + rep * 131072;
      int row = idx >> 3, c8 = idx & 7;
      const float* prow = points + (size_t)row * 61;
      u16x8 g;
      if (c8 < 7){
        f32x4 lo = *(const f32x4u*)(prow + c8*8);
        f32x4 hi = *(const f32x4u*)(prow + c8*8 + 4);
        g[0]=f2b(lo.x); g[1]=f2b(lo.y); g[2]=f2b(lo.z); g[3]=f2b(lo.w);
        g[4]=f2b(hi.x); g[5]=f2b(hi.y); g[6]=f2b(hi.z); g[7]=f2b(hi.w);
      } else {
        const float* xr = xyz + (size_t)row * 3;
        f32x4 lo = *(const f32x4u*)(prow + 56);
        g[0]=f2b(lo.x); g[1]=f2b(lo.y); g[2]=f2b(lo.z); g[3]=f2b(lo.w);
        g[4]=f2b(prow[60]);
        g[5]=f2b(xr[0]); g[6]=f2b(xr[1]); g[7]=f2b(xr[2]);
      }
      *(u16x8*)(ptsw + (size_t)row*64 + c8*8) = g;
    }
  }
}

// ---------------- k_stat0 ----------------
__global__ __launch_bounds__(256) void k_stat0(const float* lc, float* PA){
  int t = threadIdx.x;
  float a[9];
  #pragma unroll
  for (int r = 0; r < 9; ++r) a[r] = 0.f;
  size_t base = (size_t)blockIdx.x * 1024 + t;
  for (int ip = 0; ip < 4; ++ip){
    size_t p = base + (size_t)ip * 256;
    float x0 = lc[p*3], x1 = lc[p*3+1], x2 = lc[p*3+2];
    a[0]+=x0; a[1]+=x1; a[2]+=x2;
    a[3]+=x0*x0; a[4]+=x0*x1; a[5]+=x0*x2;
    a[6]+=x1*x1; a[7]+=x1*x2; a[8]+=x2*x2;
  }
  #pragma unroll
  for (int m = 1; m < 64; m <<= 1){
    #pragma unroll
    for (int r = 0; r < 9; ++r) a[r] += __shfl_xor(a[r], m);
  }
  if ((t & 63) == 0){
    float* dst = PA + (size_t)(blockIdx.x*4 + (t>>6)) * 16;
    f32x4 v0 = {a[0],a[1],a[2],a[3]}, v1 = {a[4],a[5],a[6],a[7]}, v2 = {a[8],0.f,0.f,0.f};
    *(f32x4*)dst = v0; *(f32x4*)(dst+4) = v1; *(f32x4*)(dst+8) = v2;
  }
}

// ---------------- k_red0 ----------------
__global__ __launch_bounds__(256) void k_red0(const float* PA, const float* w0, const float* b0,
                                              const float* g0, const float* be0, float* F){
  __shared__ float ms[12];
  __shared__ float a0sh[16];
  int t = threadIdx.x;
  if (t < 12){
    float s0=0,s1=0,s2=0,s3=0;
    const float* p = PA + t;
    for (int r = 0; r < 2048; r += 4){
      s0 += p[(size_t)(r+0)*16]; s1 += p[(size_t)(r+1)*16];
      s2 += p[(size_t)(r+2)*16]; s3 += p[(size_t)(r+3)*16];
    }
    ms[t] = (s0+s1)+(s2+s3);
  }
  __syncthreads();
  if (t < 16){
    float wx = w0[t*3], wy = w0[t*3+1], wz = w0[t*3+2], bb = b0[t];
    float lin = wx*ms[0] + wy*ms[1] + wz*ms[2];
    float quad = wx*wx*ms[3] + wy*wy*ms[6] + wz*wz*ms[8]
               + 2.f*(wx*wy*ms[4] + wx*wz*ms[5] + wy*wz*ms[7]);
    float S = lin + (float)NWN * bb;
    float Q = quad + 2.f*bb*lin + (float)NWN*bb*bb;
    float m = S * (1.f/NWN);
    float v = Q * (1.f/NWN) - m*m;
    float a = g0[t] * rsqrtf(v + EPSF);
    float d = be0[t] - m*a;
    a0sh[t] = a;
    F[48+t] = a*bb + d;
  }
  __syncthreads();
  if (t < 48) F[t] = a0sh[t/3] * w0[t];
}

// ---------------- k_statG ----------------
template<bool L2>
__global__ __launch_bounds__(256) void k_statG(const float* lc, const float* F, float* PB){
  __shared__ f32x4 w0p[16];
  __shared__ float w1s[256], b1fs[16];
  __shared__ __align__(16) u16 Ht[4][16*72];
  __shared__ float GS[4][16][17];
  __shared__ float SHs[4][16];
  int t = threadIdx.x;
  int w = t >> 6, l = t & 63;
  if (t < 16){
    f32x4 wv = {F[t*3], F[t*3+1], F[t*3+2], F[48+t]};
    w0p[t] = wv;
    if (L2) b1fs[t] = F[320+t];
  }
  if (L2) w1s[t] = F[64+t];
  __syncthreads();
  f32x4 acc = {0.f,0.f,0.f,0.f};
  float sh[16];
  #pragma unroll
  for (int r = 0; r < 16; ++r) sh[r] = 0.f;
  u16* Hw = &Ht[w][0];
  for (int it = 0; it < SGIT; ++it){
    size_t p = (size_t)blockIdx.x * (SGIT*256) + (size_t)it*256 + w*64 + l;
    float x0 = lc[p*3], x1 = lc[p*3+1], x2 = lc[p*3+2];
    float h[16];
    #pragma unroll
    for (int oc = 0; oc < 16; ++oc){
      f32x4 wv = w0p[oc];
      h[oc] = fmaxf(0.f, wv.x*x0 + wv.y*x1 + wv.z*x2 + wv.w);
    }
    if (L2){
      float h1[16];
      #pragma unroll
      for (int oc = 0; oc < 16; ++oc){
        const f32x4* wr = (const f32x4*)&w1s[oc*16];
        f32x4 wa = wr[0], wb = wr[1], wc = wr[2], wd = wr[3];
        float y = b1fs[oc];
        y += wa.x*h[0]  + wa.y*h[1]  + wa.z*h[2]  + wa.w*h[3];
        y += wb.x*h[4]  + wb.y*h[5]  + wb.z*h[6]  + wb.w*h[7];
        y += wc.x*h[8]  + wc.y*h[9]  + wc.z*h[10] + wc.w*h[11];
        y += wd.x*h[12] + wd.y*h[13] + wd.z*h[14] + wd.w*h[15];
        h1[oc] = fmaxf(0.f, y);
      }
      #pragma unroll
      for (int oc = 0; oc < 16; ++oc) h[oc] = h1[oc];
    }
    #pragma unroll
    for (int oc = 0; oc < 16; ++oc) sh[oc] += h[oc];
    #pragma unroll
    for (int c = 0; c < 16; ++c) Hw[c*72 + l] = f2b(h[c]);
    __syncthreads();
    #pragma unroll
    for (int tt = 0; tt < 2; ++tt){
      s16x8 af = *(const s16x8*)&Hw[(l & 15)*72 + tt*32 + (l >> 4)*8];
      acc = __builtin_amdgcn_mfma_f32_16x16x32_bf16(af, af, acc, 0, 0, 0);
    }
    __syncthreads();
  }
  #pragma unroll
  for (int r = 0; r < 4; ++r)
    GS[w][(l>>4)*4 + r][l & 15] = acc[r];
  #pragma unroll
  for (int m = 1; m < 64; m <<= 1){
    #pragma unroll
    for (int r = 0; r < 16; ++r) sh[r] += __shfl_xor(sh[r], m);
  }
  if (l == 0){
    #pragma unroll
    for (int r = 0; r < 16; ++r) SHs[w][r] = sh[r];
  }
  __syncthreads();
  {
    int i = t >> 4, j = t & 15;
    float g = GS[0][i][j] + GS[1][i][j] + GS[2][i][j] + GS[3][i][j];
    PB[(size_t)blockIdx.x*272 + t] = g;
    if (t < 16)
      PB[(size_t)blockIdx.x*272 + 256 + t] = SHs[0][t]+SHs[1][t]+SHs[2][t]+SHs[3][t];
  }
}

// ---------------- k_red1 ----------------
__global__ __launch_bounds__(256) void k_red1(const float* PB, const float* w1, const float* b1,
                                              const float* g1, const float* be1, float* F,
                                              u16* w1Bg){
  __shared__ float red[272];
  __shared__ float a1sh[16];
  int t = threadIdx.x;
  for (int e = t; e < 272; e += 256){
    float s = 0.f;
    for (int r = 0; r < SGBLK; ++r) s += PB[(size_t)r*272 + e];
    red[e] = s;
  }
  __syncthreads();
  if (t < 16){
    float wv[16];
    #pragma unroll
    for (int ic = 0; ic < 16; ++ic) wv[ic] = w1[t*16+ic];
    float lin = 0.f;
    #pragma unroll
    for (int ic = 0; ic < 16; ++ic) lin += wv[ic]*red[256+ic];
    float quad = 0.f;
    for (int i = 0; i < 16; ++i){
      float ri = 0.f;
      #pragma unroll
      for (int j = 0; j < 16; ++j) ri += wv[j]*red[i*16+j];
      quad += wv[i]*ri;
    }
    float bb = b1[t];
    float S = lin + (float)NWN * bb;
    float Q = quad + 2.f*bb*lin + (float)NWN*bb*bb;
    float m = S * (1.f/NWN);
    float v = Q * (1.f/NWN) - m*m;
    float a = g1[t] * rsqrtf(v + EPSF);
    float d = be1[t] - m*a;
    a1sh[t] = a;
    F[320+t] = a*bb + d;
  }
  __syncthreads();
  F[64 + t] = a1sh[t >> 4] * w1[t];
  if (t < 64){
    int oc = t & 15, icb = (t >> 4) * 8;
    u16x8 fr;
    #pragma unroll
    for (int j = 0; j < 8; ++j){
      int ic = icb + j;
      fr[j] = (ic < 16) ? f2b(a1sh[oc] * w1[oc*16 + ic]) : (u16)0;
    }
    *(u16x8*)&w1Bg[t*8] = fr;
  }
}

// ---------------- k_red2 ----------------
__global__ __launch_bounds__(256) void k_red2(const float* PB, const float* w2, const float* b2,
                                              const float* g2, const float* be2, float* F,
                                              u16* w2Bg){
  __shared__ float red[272];
  __shared__ float a2sh[64];
  int t = threadIdx.x;
  for (int e = t; e < 272; e += 256){
    float s = 0.f;
    for (int r = 0; r < SGBLK; ++r) s += PB[(size_t)r*272 + e];
    red[e] = s;
  }
  __syncthreads();
  if (t < 64){
    float wv[16];
    #pragma unroll
    for (int ic = 0; ic < 16; ++ic) wv[ic] = w2[t*16+ic];
    float lin = 0.f;
    #pragma unroll
    for (int ic = 0; ic < 16; ++ic) lin += wv[ic]*red[256+ic];
    float quad = 0.f;
    for (int i = 0; i < 16; ++i){
      float ri = 0.f;
      #pragma unroll
      for (int j = 0; j < 16; ++j) ri += wv[j]*red[i*16+j];
      quad += wv[i]*ri;
    }
    float bb = b2[t];
    float S = lin + (float)NWN * bb;
    float Q = quad + 2.f*bb*lin + (float)NWN*bb*bb;
    float m = S * (1.f/NWN);
    float v = Q * (1.f/NWN) - m*m;
    float a = g2[t] * rsqrtf(v + EPSF);
    float d = be2[t] - m*a;
    a2sh[t] = a;
    F[1360+t] = a*bb + d;
  }
  __syncthreads();
  for (int i = t; i < 1024; i += 256) F[336+i] = a2sh[i >> 4] * w2[i];
  {
    int ot = t >> 6, lane = t & 63;
    int oc = ot*16 + (lane & 15), icb = ((lane >> 4)) * 8;
    u16x8 fr;
    #pragma unroll
    for (int j = 0; j < 8; ++j){
      int ic = icb + j;
      fr[j] = (ic < 16) ? f2b(a2sh[oc] * w2[oc*16 + ic]) : (u16)0;
    }
    *(u16x8*)&w2Bg[t*8] = fr;
  }
}

// ---------------- K5: one point per block — MFMA WeightNet + MFMA matmul (K-major, bf16 gather) ----------------
__global__ __launch_bounds__(256) void k_main(const float* lcg, const int* nbrg,
    const u16* ptsw, const float* F,
    const u16* w1Bg, const u16* w2Bg,
    u16* npw){
  __shared__ __align__(16) u16 Gr[64*40];           // bf16 K-major: Gr[i][k], stride 40
  __shared__ __align__(16) u16 Wr[64*40];           // bf16 K-major: Wr[o][k], stride 40
  __shared__ __align__(16) u16 H0bf[32*40];         // bf16 [k][ic], ic zero-padded to 32
  __shared__ __align__(16) u16 H1bf[32*40];
  __shared__ float w0c[48], b0c[16];
  int t = threadIdx.x;
  int w = t >> 6, l = t & 63;
  int point = blockIdx.x;
  int bb = point >> 10;
  // early frag loads (registers, L2-hot)
  s16x8 w1B = *(const s16x8*)&w1Bg[l*8];
  int otA = (w & 1)*2, otB = otA + 1;
  s16x8 w2BA = *(const s16x8*)&w2Bg[(otA*64 + l)*8];
  s16x8 w2BB = *(const s16x8*)&w2Bg[(otB*64 + l)*8];
  float b1f = F[320 + (l & 15)];
  float b2fA = F[1360 + otA*16 + (l & 15)];
  float b2fB = F[1360 + otB*16 + (l & 15)];
  if (t < 48) w0c[t] = F[t];
  if (t < 16) b0c[t] = F[48+t];
  // zero-pad ic 16..31 of H0bf and H1bf
  {
    int k = t >> 3, c = 16 + (t & 7)*2;
    *(unsigned int*)&H0bf[k*40 + c] = 0u;
    *(unsigned int*)&H1bf[k*40 + c] = 0u;
  }
  // gather -> Gr K-major (one u16x8 load, 8 scalar LDS writes)
  {
    int kg = w*8 + (l >> 3), c8 = l & 7;
    int n = nbrg[(size_t)point*32 + kg];
    u16x8 g = *(const u16x8*)(ptsw + (size_t)(bb * NN + n)*64 + c8*8);
    #pragma unroll
    for (int j = 0; j < 8; ++j)
      Gr[(c8*8 + j)*40 + kg] = g[j];
  }
  __syncthreads();   // (0) w0c/b0c staged before any H0 read
  // H0 -> H0bf
  {
    int k = t >> 3, oc0 = (t & 7)*2;
    const float* xp = lcg + (size_t)point*96 + k*3;
    float x0 = xp[0], x1 = xp[1], x2 = xp[2];
    #pragma unroll
    for (int e = 0; e < 2; ++e){
      int oc = oc0 + e;
      float y = w0c[oc*3]*x0 + w0c[oc*3+1]*x1 + w0c[oc*3+2]*x2 + b0c[oc];
      H0bf[k*40 + oc] = f2b(fmaxf(0.f, y));
    }
  }
  __syncthreads();   // (1) H0bf ready
  // H1 = relu(H0 · w1f^T + b1f): 2 MFMAs, waves 0-1
  if (w < 2){
    int kt = w;
    s16x8 af = *(const s16x8*)&H0bf[(kt*16 + (l & 15))*40 + (l >> 4)*8];
    f32x4 acc = {b1f, b1f, b1f, b1f};
    acc = __builtin_amdgcn_mfma_f32_16x16x32_bf16(af, w1B, acc, 0, 0, 0);
    #pragma unroll
    for (int r = 0; r < 4; ++r)
      H1bf[(kt*16 + (l >> 4)*4 + r)*40 + (l & 15)] = f2b(fmaxf(0.f, acc[r]));
  }
  __syncthreads();   // (2) H1bf ready
  // W = relu(H1 · w2f^T + b2f): 8 MFMAs across 4 waves, K-major u16x4 writes
  {
    int kt = w >> 1;
    s16x8 af = *(const s16x8*)&H1bf[(kt*16 + (l & 15))*40 + (l >> 4)*8];
    int kbase = kt*16 + (l >> 4)*4;
    f32x4 accA = {b2fA, b2fA, b2fA, b2fA};
    accA = __builtin_amdgcn_mfma_f32_16x16x32_bf16(af, w2BA, accA, 0, 0, 0);
    u16x4 sA;
    sA[0]=f2b(fmaxf(0.f,accA[0])); sA[1]=f2b(fmaxf(0.f,accA[1]));
    sA[2]=f2b(fmaxf(0.f,accA[2])); sA[3]=f2b(fmaxf(0.f,accA[3]));
    *(u16x4*)&Wr[(otA*16 + (l & 15))*40 + kbase] = sA;
    f32x4 accB = {b2fB, b2fB, b2fB, b2fB};
    accB = __builtin_amdgcn_mfma_f32_16x16x32_bf16(af, w2BB, accB, 0, 0, 0);
    u16x4 sB;
    sB[0]=f2b(fmaxf(0.f,accB[0])); sB[1]=f2b(fmaxf(0.f,accB[1]));
    sB[2]=f2b(fmaxf(0.f,accB[2])); sB[3]=f2b(fmaxf(0.f,accB[3]));
    *(u16x4*)&Wr[(otB*16 + (l & 15))*40 + kbase] = sB;
  }
  __syncthreads();   // (3) Gr, Wr ready
  // np = G^T W: 4 MFMAs per wave, b128 frag reads, transposed u16x4 stores
  {
    int li = l & 15, lk = (l >> 4) * 8, lr = (l >> 4) * 4;
    s16x8 bfrag = *(const s16x8*)&Wr[(w*16 + li)*40 + lk];
    size_t obase = (size_t)point*4096 + (size_t)(w*16 + li)*64 + lr;
    #pragma unroll
    for (int it = 0; it < 4; ++it){
      s16x8 afrag = *(const s16x8*)&Gr[(it*16 + li)*40 + lk];
      f32x4 z = {0.f, 0.f, 0.f, 0.f};
      f32x4 d = __builtin_amdgcn_mfma_f32_16x16x32_bf16(afrag, bfrag, z, 0, 0, 0);
      u16x4 st;
      st[0] = f2b(d[0]); st[1] = f2b(d[1]); st[2] = f2b(d[2]); st[3] = f2b(d[3]);
      *(u16x4*)(npw + obase + it*16) = st;
    }
  }
}

// ---------------- k_statC: position-space stats from npw (streaming, coalesced) ----------------
__global__ __launch_bounds__(256) void k_statC(const u16* npw, float* PC){
  int t = threadIdx.x;
  float s[16], q[16];
  #pragma unroll
  for (int j = 0; j < 16; ++j){ s[j] = 0.f; q[j] = 0.f; }
  size_t rowbase = (size_t)blockIdx.x * 64;
  for (int p = 0; p < 64; ++p){
    const u16* row = npw + (rowbase + p) * 4096 + t * 16;
    u16x8 a = *(const u16x8*)row;
    u16x8 b = *(const u16x8*)(row + 8);
    #pragma unroll
    for (int j = 0; j < 8; ++j){ float v = bf(a[j]); s[j]   += v; q[j]   += v*v; }
    #pragma unroll
    for (int j = 0; j < 8; ++j){ float v = bf(b[j]); s[8+j] += v; q[8+j] += v*v; }
  }
  float* dst = PC + (size_t)blockIdx.x * 8192 + t * 16;
  #pragma unroll
  for (int j = 0; j < 16; ++j){ dst[j] = s[j]; dst[4096 + j] = q[j]; }
}

// ---------------- k_finC (position space; gc/bc permuted) ----------------
__global__ __launch_bounds__(256) void k_finC(const float* PC, const float* gc, const float* bc,
                                              float* AC, float* DC){
  int qpos = blockIdx.x * 256 + threadIdx.x;
  float s = 0.f, q = 0.f;
  for (int r = 0; r < 256; ++r){
    s += PC[(size_t)r * 8192 + qpos];
    q += PC[(size_t)r * 8192 + 4096 + qpos];
  }
  int ch = (qpos & 63)*64 + (qpos >> 6);
  float m = s * (1.f/16384.f);
  float v = q * (1.f/16384.f) - m*m;
  float a = gc[ch] * rsqrtf(v + EPSF);
  AC[qpos] = a; DC[qpos] = bc[ch] - m*a;
}

// ---------------- k_linear ----------------
__global__ __launch_bounds__(256) void k_linear(const u16* npw, const float* AC, const float* DC,
                                                const u16* lwbt, const float* lb, float* yw,
                                                float* PL){
  __shared__ u16 Al[32*72];
  __shared__ u16 Bl[64*72];
  __shared__ float cps[64], cpq[64];
  int t = threadIdx.x;
  int w = t >> 6, l = t & 63;
  int rowbase = blockIdx.x * 32;
  int mt = w & 1, np2 = w >> 1;
  f32x4 acc0 = {0.f,0.f,0.f,0.f}, acc1 = acc0;
  for (int kb = 0; kb < 4096; kb += 64){
    __syncthreads();
    {
      int r = t >> 3, c8 = t & 7;
      int kk = kb + c8*8;
      u16x8 u = *(const u16x8*)(npw + (size_t)(rowbase + r)*4096 + kk);
      f32x4 alo = *(const f32x4*)(AC + kk), ahi = *(const f32x4*)(AC + kk + 4);
      f32x4 dlo = *(const f32x4*)(DC + kk), dhi = *(const f32x4*)(DC + kk + 4);
      u16x8 o;
      o[0] = f2b(fmaxf(0.f, alo.x*bf(u[0]) + dlo.x));
      o[1] = f2b(fmaxf(0.f, alo.y*bf(u[1]) + dlo.y));
      o[2] = f2b(fmaxf(0.f, alo.z*bf(u[2]) + dlo.z));
      o[3] = f2b(fmaxf(0.f, alo.w*bf(u[3]) + dlo.w));
      o[4] = f2b(fmaxf(0.f, ahi.x*bf(u[4]) + dhi.x));
      o[5] = f2b(fmaxf(0.f, ahi.y*bf(u[5]) + dhi.y));
      o[6] = f2b(fmaxf(0.f, ahi.z*bf(u[6]) + dhi.z));
      o[7] = f2b(fmaxf(0.f, ahi.w*bf(u[7]) + dhi.w));
      *(u16x8*)&Al[r*72 + c8*8] = o;
    }
    #pragma unroll
    for (int jj = 0; jj < 2; ++jj){
      int n = (t >> 3) + jj*32, c8 = t & 7;
      u16x8 u = *(const u16x8*)(lwbt + (size_t)n*4096 + kb + c8*8);
      *(u16x8*)&Bl[n*72 + c8*8] = u;
    }
    __syncthreads();
    #pragma unroll
    for (int ks = 0; ks < 2; ++ks){
      s16x8 af  = *(const s16x8*)&Al[(mt*16 + (l & 15))*72 + ks*32 + (l >> 4)*8];
      s16x8 bf0 = *(const s16x8*)&Bl[((np2*2    )*16 + (l & 15))*72 + ks*32 + (l >> 4)*8];
      s16x8 bf1 = *(const s16x8*)&Bl[((np2*2 + 1)*16 + (l & 15))*72 + ks*32 + (l >> 4)*8];
      acc0 = __builtin_amdgcn_mfma_f32_16x16x32_bf16(af, bf0, acc0, 0, 0, 0);
      acc1 = __builtin_amdgcn_mfma_f32_16x16x32_bf16(af, bf1, acc1, 0, 0, 0);
    }
  }
  int col0 = np2*32 + (l & 15), col1 = col0 + 16;
  float lb0 = lb[col0], lb1 = lb[col1];
  float s0 = 0.f, q0 = 0.f, s1 = 0.f, q1 = 0.f;
  if (t < 64){ cps[t] = 0.f; cpq[t] = 0.f; }
  __syncthreads();
  #pragma unroll
  for (int r = 0; r < 4; ++r){
    int row = rowbase + mt*16 + (l >> 4)*4 + r;
    float y0 = acc0[r] + lb0;
    float y1 = acc1[r] + lb1;
    yw[(size_t)row*64 + col0] = y0;
    yw[(size_t)row*64 + col1] = y1;
    s0 += y0; q0 += y0*y0; s1 += y1; q1 += y1*y1;
  }
  atomicAdd(&cps[col0], s0); atomicAdd(&cpq[col0], q0);
  atomicAdd(&cps[col1], s1); atomicAdd(&cpq[col1], q1);
  __syncthreads();
  if (t < 64){
    PL[blockIdx.x*128 + t]      = cps[t];
    PL[blockIdx.x*128 + 64 + t] = cpq[t];
  }
}

// ---------------- k_redF ----------------
__global__ __launch_bounds__(128) void k_redF(const float* PL, float* SL){
  int t = threadIdx.x;
  float s = 0.f;
  for (int b = 0; b < 512; ++b) s += PL[b*128 + t];
  SL[t] = s;
}

// ---------------- k_final ----------------
__global__ __launch_bounds__(256) void k_final(const float* yw, const float* SL,
                                               const float* gl, const float* bl, float* out){
  int e = (blockIdx.x * 256 + threadIdx.x) * 4;
  int o = e & 63;
  f32x4 y = *(const f32x4*)(yw + e);
  f32x4 r;
  #pragma unroll
  for (int j = 0; j < 4; ++j){
    float m = SL[o+j] * (1.f/16384.f);
    float v = SL[64+o+j] * (1.f/16384.f) - m*m;
    float a = gl[o+j] * rsqrtf(v + EPSF);
    float d = bl[o+j] - m*a;
    r[j] = fmaxf(0.f, a*y[j] + d);
  }
  *(f32x4*)(out + 49152 + e) = r;
}

extern "C" void kernel_launch(void* const* d_in, const int* in_sizes, int n_in,
                              void* d_out, int out_size, void* d_ws, size_t ws_size,
                              hipStream_t stream){
  (void)in_sizes; (void)n_in; (void)out_size; (void)ws_size;
  const float* xyz    = (const float*)d_in[0];
  const float* points = (const float*)d_in[1];
  const float* lc     = (const float*)d_in[2];
  const int*   nbrl   = (const int*)d_in[3];
  const int*   didx   = (const int*)d_in[4];
  const float* w0 = (const float*)d_in[5];
  const float* b0 = (const float*)d_in[6];
  const float* g0 = (const float*)d_in[7];
  const float* be0= (const float*)d_in[8];
  const float* w1 = (const float*)d_in[9];
  const float* b1 = (const float*)d_in[10];
  const float* g1 = (const float*)d_in[11];
  const float* be1= (const float*)d_in[12];
  const float* w2 = (const float*)d_in[13];
  const float* b2 = (const float*)d_in[14];
  const float* g2 = (const float*)d_in[15];
  const float* be2= (const float*)d_in[16];
  const float* gc = (const float*)d_in[17];
  const float* bc = (const float*)d_in[18];
  const float* lw = (const float*)d_in[19];
  const float* lb = (const float*)d_in[20];
  const float* gl = (const float*)d_in[21];
  const float* bl = (const float*)d_in[22];
  float* out = (float*)d_out;
  char* ws = (char*)d_ws;

  float* F   = (float*)ws;           // 1536
  float* SL  = F + 1536;             // 128
  float* AC  = SL + 128;             // 4096
  float* DC  = AC + 4096;            // 4096
  float* PA  = DC + 4096;            // 32768
  float* PB1 = PA + 32768;           // 139264
  float* PB2 = PB1 + 139264;         // 139264
  float* PL  = PB2 + 139264;         // 65536
  u16*  w1Bg = (u16*)(PL + 65536);   // 512 u16
  u16*  w2Bg = w1Bg + 512;           // 2048 u16
  float* PC  = (float*)(ws + 4194304);                        // 8 MB
  u16*  npw  = (u16*)(ws + 4194304 + 8388608);                // 128 MB bf16 (transposed)
  float* yw  = (float*)(ws + 4194304 + 8388608 + 134217728);  // 4 MB f32
  u16*  lwbt = (u16*)(ws + 4194304 + 8388608 + 134217728 + 4194304); // 512 KB (permuted)
  u16*  ptsw = (u16*)(ws + 4194304 + 8388608 + 134217728 + 4194304 + 1048576); // 8 MB bf16

  k_init  <<<640,   256, 0, stream>>>(xyz, didx, out, lw, lwbt, points, ptsw);
  k_stat0 <<<512,   256, 0, stream>>>(lc, PA);
  k_red0  <<<1,     256, 0, stream>>>(PA, w0, b0, g0, be0, F);
  k_statG<false><<<SGBLK, 256, 0, stream>>>(lc, F, PB1);
  k_red1  <<<1,     256, 0, stream>>>(PB1, w1, b1, g1, be1, F, w1Bg);
  k_statG<true> <<<SGBLK, 256, 0, stream>>>(lc, F, PB2);
  k_red2  <<<1,     256, 0, stream>>>(PB2, w2, b2, g2, be2, F, w2Bg);
  k_main  <<<16384, 256, 0, stream>>>(lc, nbrl, ptsw, F, w1Bg, w2Bg, npw);
  k_statC <<<256,   256, 0, stream>>>(npw, PC);
  k_finC  <<<16,    256, 0, stream>>>(PC, gc, bc, AC, DC);
  k_linear<<<512,   256, 0, stream>>>(npw, AC, DC, lwbt, lb, yw, PL);
  k_redF  <<<1,     128, 0, stream>>>(PL, SL);
  k_final <<<1024,  256, 0, stream>>>(yw, SL, gl, bl, out);
}

// Round 18
// 258.696 us; speedup vs baseline: 6.8220x; 1.0308x over previous
//
#include <hip/hip_runtime.h>
#include <hip/hip_bf16.h>

#define BB 16
#define NN 4096
#define NPOINTS 1024
#define KK 32
#define NPTS (BB*NPOINTS)        // 16384
#define NWN  (BB*NPOINTS*KK)     // 524288
#define EPSF 1e-5f
#define SGBLK 512
#define SGIT  4

typedef unsigned short u16;
typedef u16  u16x8 __attribute__((ext_vector_type(8)));
typedef u16  u16x4 __attribute__((ext_vector_type(4)));
typedef short s16x8 __attribute__((ext_vector_type(8)));
typedef float f32x4 __attribute__((ext_vector_type(4)));
typedef float f32x4u __attribute__((ext_vector_type(4), aligned(4)));

__device__ __forceinline__ float bf(u16 u){
  union { unsigned int i; float f; } v; v.i = ((unsigned int)u) << 16; return v.f;
}
__device__ __forceinline__ u16 f2b(float f){
  __hip_bfloat16 h = __float2bfloat16(f);
  union { __hip_bfloat16 hh; u16 u; } v; v.hh = h; return v.u;
}

// F layout (folded weights): [0..47] w0f, [48..63] b0f, [64..319] w1f,
// [320..335] b1f, [336..1359] w2f, [1360..1423] b2f
// npw: transposed position space q = o*64 + i  (original channel ch = i*64 + o)
// ptsw[B*N][64] bf16: pre-converted concat(points, xyz) rows (gather table)
// Gr LDS layout: K-major with XOR-swizzled 16B k-blocks (write bank fix, round 18)
// NOTE (round 15): device atomics bypass L2 on MI355X -> keep stats streaming.

// ---------------- k_init: newxyz (0..63) + lwbt (64..127) + ptsw build (128..639) ----------------
__global__ __launch_bounds__(256) void k_init(const float* xyz, const int* didx, float* out,
                                              const float* lw, u16* lwbt,
                                              const float* points, u16* ptsw){
  int t = threadIdx.x;
  if (blockIdx.x < 64){
    int p = blockIdx.x * 256 + t;
    int b = p >> 10;
    int idx = didx[p];
    const float* src = xyz + ((size_t)(b * NN + idx)) * 3;
    float* dst = out + (size_t)p * 3;
    dst[0] = src[0]; dst[1] = src[1]; dst[2] = src[2];
  } else if (blockIdx.x < 128){
    __shared__ float T[64][65];
    int ib = blockIdx.x - 64;
    int kb = ib * 64;
    {
      int k = t >> 2, c4 = t & 3;
      #pragma unroll
      for (int j = 0; j < 4; ++j)
        *(f32x4*)&T[k][c4*16 + j*4] = *(const f32x4*)(lw + (size_t)(kb + k)*64 + c4*16 + j*4);
    }
    __syncthreads();
    {
      int n = t >> 2, k4 = t & 3;
      #pragma unroll
      for (int j = 0; j < 16; ++j){
        int k = k4*16 + j;
        lwbt[(size_t)n*4096 + k*64 + ib] = f2b(T[k][n]);
      }
    }
  } else {
    int gid0 = (blockIdx.x - 128) * 256 + t;
    #pragma unroll
    for (int rep = 0; rep < 4; ++rep){
      int idx = gid0 + rep * 131072;
      int row = idx >> 3, c8 = idx & 7;
      const float* prow = points + (size_t)row * 61;
      u16x8 g;
      if (c8 < 7){
        f32x4 lo = *(const f32x4u*)(prow + c8*8);
        f32x4 hi = *(const f32x4u*)(prow + c8*8 + 4);
        g[0]=f2b(lo.x); g[1]=f2b(lo.y); g[2]=f2b(lo.z); g[3]=f2b(lo.w);
        g[4]=f2b(hi.x); g[5]=f2b(hi.y); g[6]=f2b(hi.z); g[7]=f2b(hi.w);
      } else {
        const float* xr = xyz + (size_t)row * 3;
        f32x4 lo = *(const f32x4u*)(prow + 56);
        g[0]=f2b(lo.x); g[1]=f2b(lo.y); g[2]=f2b(lo.z); g[3]=f2b(lo.w);
        g[4]=f2b(prow[60]);
        g[5]=f2b(xr[0]); g[6]=f2b(xr[1]); g[7]=f2b(xr[2]);
      }
      *(u16x8*)(ptsw + (size_t)row*64 + c8*8) = g;
    }
  }
}

// ---------------- k_stat0 ----------------
__global__ __launch_bounds__(256) void k_stat0(const float* lc, float* PA){
  int t = threadIdx.x;
  float a[9];
  #pragma unroll
  for (int r = 0; r < 9; ++r) a[r] = 0.f;
  size_t base = (size_t)blockIdx.x * 1024 + t;
  for (int ip = 0; ip < 4; ++ip){
    size_t p = base + (size_t)ip * 256;
    float x0 = lc[p*3], x1 = lc[p*3+1], x2 = lc[p*3+2];
    a[0]+=x0; a[1]+=x1; a[2]+=x2;
    a[3]+=x0*x0; a[4]+=x0*x1; a[5]+=x0*x2;
    a[6]+=x1*x1; a[7]+=x1*x2; a[8]+=x2*x2;
  }
  #pragma unroll
  for (int m = 1; m < 64; m <<= 1){
    #pragma unroll
    for (int r = 0; r < 9; ++r) a[r] += __shfl_xor(a[r], m);
  }
  if ((t & 63) == 0){
    float* dst = PA + (size_t)(blockIdx.x*4 + (t>>6)) * 16;
    f32x4 v0 = {a[0],a[1],a[2],a[3]}, v1 = {a[4],a[5],a[6],a[7]}, v2 = {a[8],0.f,0.f,0.f};
    *(f32x4*)dst = v0; *(f32x4*)(dst+4) = v1; *(f32x4*)(dst+8) = v2;
  }
}

// ---------------- k_red0 ----------------
__global__ __launch_bounds__(256) void k_red0(const float* PA, const float* w0, const float* b0,
                                              const float* g0, const float* be0, float* F){
  __shared__ float ms[12];
  __shared__ float a0sh[16];
  int t = threadIdx.x;
  if (t < 12){
    float s0=0,s1=0,s2=0,s3=0;
    const float* p = PA + t;
    for (int r = 0; r < 2048; r += 4){
      s0 += p[(size_t)(r+0)*16]; s1 += p[(size_t)(r+1)*16];
      s2 += p[(size_t)(r+2)*16]; s3 += p[(size_t)(r+3)*16];
    }
    ms[t] = (s0+s1)+(s2+s3);
  }
  __syncthreads();
  if (t < 16){
    float wx = w0[t*3], wy = w0[t*3+1], wz = w0[t*3+2], bb = b0[t];
    float lin = wx*ms[0] + wy*ms[1] + wz*ms[2];
    float quad = wx*wx*ms[3] + wy*wy*ms[6] + wz*wz*ms[8]
               + 2.f*(wx*wy*ms[4] + wx*wz*ms[5] + wy*wz*ms[7]);
    float S = lin + (float)NWN * bb;
    float Q = quad + 2.f*bb*lin + (float)NWN*bb*bb;
    float m = S * (1.f/NWN);
    float v = Q * (1.f/NWN) - m*m;
    float a = g0[t] * rsqrtf(v + EPSF);
    float d = be0[t] - m*a;
    a0sh[t] = a;
    F[48+t] = a*bb + d;
  }
  __syncthreads();
  if (t < 48) F[t] = a0sh[t/3] * w0[t];
}

// ---------------- k_statG1: h0 Gram (VALU h0, MFMA Gram) ----------------
__global__ __launch_bounds__(256) void k_statG1(const float* lc, const float* F, float* PB){
  __shared__ f32x4 w0p[16];
  __shared__ __align__(16) u16 Ht[4][16*72];
  __shared__ float GS[4][16][17];
  __shared__ float SHs[4][16];
  int t = threadIdx.x;
  int w = t >> 6, l = t & 63;
  if (t < 16){
    f32x4 wv = {F[t*3], F[t*3+1], F[t*3+2], F[48+t]};
    w0p[t] = wv;
  }
  __syncthreads();
  f32x4 acc = {0.f,0.f,0.f,0.f};
  float sh[16];
  #pragma unroll
  for (int r = 0; r < 16; ++r) sh[r] = 0.f;
  u16* Hw = &Ht[w][0];
  for (int it = 0; it < SGIT; ++it){
    size_t p = (size_t)blockIdx.x * (SGIT*256) + (size_t)it*256 + w*64 + l;
    float x0 = lc[p*3], x1 = lc[p*3+1], x2 = lc[p*3+2];
    float h[16];
    #pragma unroll
    for (int oc = 0; oc < 16; ++oc){
      f32x4 wv = w0p[oc];
      h[oc] = fmaxf(0.f, wv.x*x0 + wv.y*x1 + wv.z*x2 + wv.w);
      sh[oc] += h[oc];
    }
    #pragma unroll
    for (int c = 0; c < 16; ++c) Hw[c*72 + l] = f2b(h[c]);
    __syncthreads();
    #pragma unroll
    for (int tt = 0; tt < 2; ++tt){
      s16x8 af = *(const s16x8*)&Hw[(l & 15)*72 + tt*32 + (l >> 4)*8];
      acc = __builtin_amdgcn_mfma_f32_16x16x32_bf16(af, af, acc, 0, 0, 0);
    }
    __syncthreads();
  }
  #pragma unroll
  for (int r = 0; r < 4; ++r)
    GS[w][(l>>4)*4 + r][l & 15] = acc[r];
  #pragma unroll
  for (int m = 1; m < 64; m <<= 1){
    #pragma unroll
    for (int r = 0; r < 16; ++r) sh[r] += __shfl_xor(sh[r], m);
  }
  if (l == 0){
    #pragma unroll
    for (int r = 0; r < 16; ++r) SHs[w][r] = sh[r];
  }
  __syncthreads();
  {
    int i = t >> 4, j = t & 15;
    float g = GS[0][i][j] + GS[1][i][j] + GS[2][i][j] + GS[3][i][j];
    PB[(size_t)blockIdx.x*272 + t] = g;
    if (t < 16)
      PB[(size_t)blockIdx.x*272 + 256 + t] = SHs[0][t]+SHs[1][t]+SHs[2][t]+SHs[3][t];
  }
}

// ---------------- k_statG2: h1 Gram (MFMA h1 via w1Bg + MFMA Gram) ----------------
__global__ __launch_bounds__(256) void k_statG2(const float* lc, const float* F,
                                                const u16* w1Bg, float* PB){
  __shared__ f32x4 w0p[16];
  __shared__ __align__(16) u16 Ht0[4][64*40];   // per-wave [pt][ic] bf16, ic padded to 32
  __shared__ __align__(16) u16 Ht1[4][16*72];   // per-wave [ch][pt] bf16 (Gram input)
  __shared__ float GS[4][16][17];
  __shared__ float SHs[4][16];
  int t = threadIdx.x;
  int w = t >> 6, l = t & 63;
  if (t < 16){
    f32x4 wv = {F[t*3], F[t*3+1], F[t*3+2], F[48+t]};
    w0p[t] = wv;
  }
  s16x8 w1B = *(const s16x8*)&w1Bg[l*8];
  float b1f = F[320 + (l & 15)];
  u16* H0w = &Ht0[w][0];
  u16* H1w = &Ht1[w][0];
  // zero-pad ic 16..31 of own point-row
  {
    u16x8 z8 = {0,0,0,0,0,0,0,0};
    *(u16x8*)&H0w[l*40 + 16] = z8;
    *(u16x8*)&H0w[l*40 + 24] = z8;
  }
  __syncthreads();   // w0p + pads visible
  f32x4 acc = {0.f,0.f,0.f,0.f};
  float shloc = 0.f;
  for (int it = 0; it < SGIT; ++it){
    size_t p = (size_t)blockIdx.x * (SGIT*256) + (size_t)it*256 + w*64 + l;
    float x0 = lc[p*3], x1 = lc[p*3+1], x2 = lc[p*3+2];
    u16x8 p0, p1;
    #pragma unroll
    for (int oc = 0; oc < 8; ++oc){
      f32x4 wv = w0p[oc];
      p0[oc] = f2b(fmaxf(0.f, wv.x*x0 + wv.y*x1 + wv.z*x2 + wv.w));
    }
    #pragma unroll
    for (int oc = 0; oc < 8; ++oc){
      f32x4 wv = w0p[8+oc];
      p1[oc] = f2b(fmaxf(0.f, wv.x*x0 + wv.y*x1 + wv.z*x2 + wv.w));
    }
    *(u16x8*)&H0w[l*40]     = p0;
    *(u16x8*)&H0w[l*40 + 8] = p1;
    __syncthreads();   // (a) H0 tile ready
    // h1 = relu(H0 · w1f^T + b1f): 4 m-tiles per wave; write Ht1 [ch][pt]
    #pragma unroll
    for (int mt = 0; mt < 4; ++mt){
      s16x8 af = *(const s16x8*)&H0w[(mt*16 + (l & 15))*40 + (l >> 4)*8];
      f32x4 c = {b1f, b1f, b1f, b1f};
      c = __builtin_amdgcn_mfma_f32_16x16x32_bf16(af, w1B, c, 0, 0, 0);
      #pragma unroll
      for (int r = 0; r < 4; ++r){
        float v = fmaxf(0.f, c[r]);
        shloc += v;
        H1w[(l & 15)*72 + mt*16 + (l >> 4)*4 + r] = f2b(v);
      }
    }
    __syncthreads();   // (b) H1 ready
    #pragma unroll
    for (int tt = 0; tt < 2; ++tt){
      s16x8 afg = *(const s16x8*)&H1w[(l & 15)*72 + tt*32 + (l >> 4)*8];
      acc = __builtin_amdgcn_mfma_f32_16x16x32_bf16(afg, afg, acc, 0, 0, 0);
    }
    __syncthreads();   // (c) Gram reads done before next-iter overwrite
  }
  #pragma unroll
  for (int r = 0; r < 4; ++r)
    GS[w][(l>>4)*4 + r][l & 15] = acc[r];
  // shloc holds partial for oc = l&15 over this lane-group's rows; sum the 4 groups
  shloc += __shfl_xor(shloc, 16);
  shloc += __shfl_xor(shloc, 32);
  if (l < 16) SHs[w][l] = shloc;
  __syncthreads();
  {
    int i = t >> 4, j = t & 15;
    float g = GS[0][i][j] + GS[1][i][j] + GS[2][i][j] + GS[3][i][j];
    PB[(size_t)blockIdx.x*272 + t] = g;
    if (t < 16)
      PB[(size_t)blockIdx.x*272 + 256 + t] = SHs[0][t]+SHs[1][t]+SHs[2][t]+SHs[3][t];
  }
}

// ---------------- k_red1 ----------------
__global__ __launch_bounds__(256) void k_red1(const float* PB, const float* w1, const float* b1,
                                              const float* g1, const float* be1, float* F,
                                              u16* w1Bg){
  __shared__ float red[272];
  __shared__ float a1sh[16];
  int t = threadIdx.x;
  for (int e = t; e < 272; e += 256){
    float s = 0.f;
    for (int r = 0; r < SGBLK; ++r) s += PB[(size_t)r*272 + e];
    red[e] = s;
  }
  __syncthreads();
  if (t < 16){
    float wv[16];
    #pragma unroll
    for (int ic = 0; ic < 16; ++ic) wv[ic] = w1[t*16+ic];
    float lin = 0.f;
    #pragma unroll
    for (int ic = 0; ic < 16; ++ic) lin += wv[ic]*red[256+ic];
    float quad = 0.f;
    for (int i = 0; i < 16; ++i){
      float ri = 0.f;
      #pragma unroll
      for (int j = 0; j < 16; ++j) ri += wv[j]*red[i*16+j];
      quad += wv[i]*ri;
    }
    float bb = b1[t];
    float S = lin + (float)NWN * bb;
    float Q = quad + 2.f*bb*lin + (float)NWN*bb*bb;
    float m = S * (1.f/NWN);
    float v = Q * (1.f/NWN) - m*m;
    float a = g1[t] * rsqrtf(v + EPSF);
    float d = be1[t] - m*a;
    a1sh[t] = a;
    F[320+t] = a*bb + d;
  }
  __syncthreads();
  F[64 + t] = a1sh[t >> 4] * w1[t];
  if (t < 64){
    int oc = t & 15, icb = (t >> 4) * 8;
    u16x8 fr;
    #pragma unroll
    for (int j = 0; j < 8; ++j){
      int ic = icb + j;
      fr[j] = (ic < 16) ? f2b(a1sh[oc] * w1[oc*16 + ic]) : (u16)0;
    }
    *(u16x8*)&w1Bg[t*8] = fr;
  }
}

// ---------------- k_red2 ----------------
__global__ __launch_bounds__(256) void k_red2(const float* PB, const float* w2, const float* b2,
                                              const float* g2, const float* be2, float* F,
                                              u16* w2Bg){
  __shared__ float red[272];
  __shared__ float a2sh[64];
  int t = threadIdx.x;
  for (int e = t; e < 272; e += 256){
    float s = 0.f;
    for (int r = 0; r < SGBLK; ++r) s += PB[(size_t)r*272 + e];
    red[e] = s;
  }
  __syncthreads();
  if (t < 64){
    float wv[16];
    #pragma unroll
    for (int ic = 0; ic < 16; ++ic) wv[ic] = w2[t*16+ic];
    float lin = 0.f;
    #pragma unroll
    for (int ic = 0; ic < 16; ++ic) lin += wv[ic]*red[256+ic];
    float quad = 0.f;
    for (int i = 0; i < 16; ++i){
      float ri = 0.f;
      #pragma unroll
      for (int j = 0; j < 16; ++j) ri += wv[j]*red[i*16+j];
      quad += wv[i]*ri;
    }
    float bb = b2[t];
    float S = lin + (float)NWN * bb;
    float Q = quad + 2.f*bb*lin + (float)NWN*bb*bb;
    float m = S * (1.f/NWN);
    float v = Q * (1.f/NWN) - m*m;
    float a = g2[t] * rsqrtf(v + EPSF);
    float d = be2[t] - m*a;
    a2sh[t] = a;
    F[1360+t] = a*bb + d;
  }
  __syncthreads();
  for (int i = t; i < 1024; i += 256) F[336+i] = a2sh[i >> 4] * w2[i];
  {
    int ot = t >> 6, lane = t & 63;
    int oc = ot*16 + (lane & 15), icb = ((lane >> 4)) * 8;
    u16x8 fr;
    #pragma unroll
    for (int j = 0; j < 8; ++j){
      int ic = icb + j;
      fr[j] = (ic < 16) ? f2b(a2sh[oc] * w2[oc*16 + ic]) : (u16)0;
    }
    *(u16x8*)&w2Bg[t*8] = fr;
  }
}

// ---------------- K5: one point per block — MFMA WeightNet + MFMA matmul (swizzled K-major Gr) ----------------
__global__ __launch_bounds__(256) void k_main(const float* lcg, const int* nbrg,
    const u16* ptsw, const float* F,
    const u16* w1Bg, const u16* w2Bg,
    u16* npw){
  __shared__ __align__(16) u16 Gr[64*40];           // bf16 K-major, 16B k-blocks XOR-swizzled by (ch>>3)&3
  __shared__ __align__(16) u16 Wr[64*40];           // bf16 K-major: Wr[o][k], stride 40 (unswizzled)
  __shared__ __align__(16) u16 H0bf[32*40];
  __shared__ __align__(16) u16 H1bf[32*40];
  __shared__ float w0c[48], b0c[16];
  int t = threadIdx.x;
  int w = t >> 6, l = t & 63;
  int point = blockIdx.x;
  int bb = point >> 10;
  s16x8 w1B = *(const s16x8*)&w1Bg[l*8];
  int otA = (w & 1)*2, otB = otA + 1;
  s16x8 w2BA = *(const s16x8*)&w2Bg[(otA*64 + l)*8];
  s16x8 w2BB = *(const s16x8*)&w2Bg[(otB*64 + l)*8];
  float b1f = F[320 + (l & 15)];
  float b2fA = F[1360 + otA*16 + (l & 15)];
  float b2fB = F[1360 + otB*16 + (l & 15)];
  if (t < 48) w0c[t] = F[t];
  if (t < 16) b0c[t] = F[48+t];
  {
    int k = t >> 3, c = 16 + (t & 7)*2;
    *(unsigned int*)&H0bf[k*40 + c] = 0u;
    *(unsigned int*)&H1bf[k*40 + c] = 0u;
  }
  // gather -> Gr swizzled K-major: logical kg -> physical block (kg>>3)^(ch>>3 & 3)
  {
    int kg = w*8 + (l >> 3), c8 = l & 7;
    int n = nbrg[(size_t)point*32 + kg];
    u16x8 g = *(const u16x8*)(ptsw + (size_t)(bb * NN + n)*64 + c8*8);
    int kphys = ((w ^ (c8 & 3)) << 3) + (l >> 3);   // kg>>3 == w, kg&7 == l>>3
    #pragma unroll
    for (int j = 0; j < 8; ++j)
      Gr[(c8*8 + j)*40 + kphys] = g[j];
  }
  __syncthreads();   // (0) w0c/b0c staged before H0 read
  // H0 -> H0bf
  {
    int k = t >> 3, oc0 = (t & 7)*2;
    const float* xp = lcg + (size_t)point*96 + k*3;
    float x0 = xp[0], x1 = xp[1], x2 = xp[2];
    #pragma unroll
    for (int e = 0; e < 2; ++e){
      int oc = oc0 + e;
      float y = w0c[oc*3]*x0 + w0c[oc*3+1]*x1 + w0c[oc*3+2]*x2 + b0c[oc];
      H0bf[k*40 + oc] = f2b(fmaxf(0.f, y));
    }
  }
  __syncthreads();   // (1) H0bf ready
  if (w < 2){
    int kt = w;
    s16x8 af = *(const s16x8*)&H0bf[(kt*16 + (l & 15))*40 + (l >> 4)*8];
    f32x4 acc = {b1f, b1f, b1f, b1f};
    acc = __builtin_amdgcn_mfma_f32_16x16x32_bf16(af, w1B, acc, 0, 0, 0);
    #pragma unroll
    for (int r = 0; r < 4; ++r)
      H1bf[(kt*16 + (l >> 4)*4 + r)*40 + (l & 15)] = f2b(fmaxf(0.f, acc[r]));
  }
  __syncthreads();   // (2) H1bf ready
  {
    int kt = w >> 1;
    s16x8 af = *(const s16x8*)&H1bf[(kt*16 + (l & 15))*40 + (l >> 4)*8];
    int kbase = kt*16 + (l >> 4)*4;
    f32x4 accA = {b2fA, b2fA, b2fA, b2fA};
    accA = __builtin_amdgcn_mfma_f32_16x16x32_bf16(af, w2BA, accA, 0, 0, 0);
    u16x4 sA;
    sA[0]=f2b(fmaxf(0.f,accA[0])); sA[1]=f2b(fmaxf(0.f,accA[1]));
    sA[2]=f2b(fmaxf(0.f,accA[2])); sA[3]=f2b(fmaxf(0.f,accA[3]));
    *(u16x4*)&Wr[(otA*16 + (l & 15))*40 + kbase] = sA;
    f32x4 accB = {b2fB, b2fB, b2fB, b2fB};
    accB = __builtin_amdgcn_mfma_f32_16x16x32_bf16(af, w2BB, accB, 0, 0, 0);
    u16x4 sB;
    sB[0]=f2b(fmaxf(0.f,accB[0])); sB[1]=f2b(fmaxf(0.f,accB[1]));
    sB[2]=f2b(fmaxf(0.f,accB[2])); sB[3]=f2b(fmaxf(0.f,accB[3]));
    *(u16x4*)&Wr[(otB*16 + (l & 15))*40 + kbase] = sB;
  }
  __syncthreads();   // (3) Gr, Wr ready
  // np = G^T W: swizzle-aware A-frag reads
  {
    int li = l & 15, lkb = l >> 4, lr = (l >> 4) * 4;
    s16x8 bfrag = *(const s16x8*)&Wr[(w*16 + li)*40 + lkb*8];
    size_t obase = (size_t)point*4096 + (size_t)(w*16 + li)*64 + lr;
    #pragma unroll
    for (int it = 0; it < 4; ++it){
      int ch = it*16 + li;
      int key = (ch >> 3) & 3;
      s16x8 afrag = *(const s16x8*)&Gr[ch*40 + ((lkb ^ key) << 3)];
      f32x4 z = {0.f, 0.f, 0.f, 0.f};
      f32x4 d = __builtin_amdgcn_mfma_f32_16x16x32_bf16(afrag, bfrag, z, 0, 0, 0);
      u16x4 st;
      st[0] = f2b(d[0]); st[1] = f2b(d[1]); st[2] = f2b(d[2]); st[3] = f2b(d[3]);
      *(u16x4*)(npw + obase + it*16) = st;
    }
  }
}

// ---------------- k_statC ----------------
__global__ __launch_bounds__(256) void k_statC(const u16* npw, float* PC){
  int t = threadIdx.x;
  float s[16], q[16];
  #pragma unroll
  for (int j = 0; j < 16; ++j){ s[j] = 0.f; q[j] = 0.f; }
  size_t rowbase = (size_t)blockIdx.x * 64;
  for (int p = 0; p < 64; ++p){
    const u16* row = npw + (rowbase + p) * 4096 + t * 16;
    u16x8 a = *(const u16x8*)row;
    u16x8 b = *(const u16x8*)(row + 8);
    #pragma unroll
    for (int j = 0; j < 8; ++j){ float v = bf(a[j]); s[j]   += v; q[j]   += v*v; }
    #pragma unroll
    for (int j = 0; j < 8; ++j){ float v = bf(b[j]); s[8+j] += v; q[8+j] += v*v; }
  }
  float* dst = PC + (size_t)blockIdx.x * 8192 + t * 16;
  #pragma unroll
  for (int j = 0; j < 16; ++j){ dst[j] = s[j]; dst[4096 + j] = q[j]; }
}

// ---------------- k_finC (position space; gc/bc permuted) ----------------
__global__ __launch_bounds__(256) void k_finC(const float* PC, const float* gc, const float* bc,
                                              float* AC, float* DC){
  int qpos = blockIdx.x * 256 + threadIdx.x;
  float s = 0.f, q = 0.f;
  for (int r = 0; r < 256; ++r){
    s += PC[(size_t)r * 8192 + qpos];
    q += PC[(size_t)r * 8192 + 4096 + qpos];
  }
  int ch = (qpos & 63)*64 + (qpos >> 6);
  float m = s * (1.f/16384.f);
  float v = q * (1.f/16384.f) - m*m;
  float a = gc[ch] * rsqrtf(v + EPSF);
  AC[qpos] = a; DC[qpos] = bc[ch] - m*a;
}

// ---------------- k_linear ----------------
__global__ __launch_bounds__(256) void k_linear(const u16* npw, const float* AC, const float* DC,
                                                const u16* lwbt, const float* lb, float* yw,
                                                float* PL){
  __shared__ u16 Al[32*72];
  __shared__ u16 Bl[64*72];
  __shared__ float cps[64], cpq[64];
  int t = threadIdx.x;
  int w = t >> 6, l = t & 63;
  int rowbase = blockIdx.x * 32;
  int mt = w & 1, np2 = w >> 1;
  f32x4 acc0 = {0.f,0.f,0.f,0.f}, acc1 = acc0;
  for (int kb = 0; kb < 4096; kb += 64){
    __syncthreads();
    {
      int r = t >> 3, c8 = t & 7;
      int kk = kb + c8*8;
      u16x8 u = *(const u16x8*)(npw + (size_t)(rowbase + r)*4096 + kk);
      f32x4 alo = *(const f32x4*)(AC + kk), ahi = *(const f32x4*)(AC + kk + 4);
      f32x4 dlo = *(const f32x4*)(DC + kk), dhi = *(const f32x4*)(DC + kk + 4);
      u16x8 o;
      o[0] = f2b(fmaxf(0.f, alo.x*bf(u[0]) + dlo.x));
      o[1] = f2b(fmaxf(0.f, alo.y*bf(u[1]) + dlo.y));
      o[2] = f2b(fmaxf(0.f, alo.z*bf(u[2]) + dlo.z));
      o[3] = f2b(fmaxf(0.f, alo.w*bf(u[3]) + dlo.w));
      o[4] = f2b(fmaxf(0.f, ahi.x*bf(u[4]) + dhi.x));
      o[5] = f2b(fmaxf(0.f, ahi.y*bf(u[5]) + dhi.y));
      o[6] = f2b(fmaxf(0.f, ahi.z*bf(u[6]) + dhi.z));
      o[7] = f2b(fmaxf(0.f, ahi.w*bf(u[7]) + dhi.w));
      *(u16x8*)&Al[r*72 + c8*8] = o;
    }
    #pragma unroll
    for (int jj = 0; jj < 2; ++jj){
      int n = (t >> 3) + jj*32, c8 = t & 7;
      u16x8 u = *(const u16x8*)(lwbt + (size_t)n*4096 + kb + c8*8);
      *(u16x8*)&Bl[n*72 + c8*8] = u;
    }
    __syncthreads();
    #pragma unroll
    for (int ks = 0; ks < 2; ++ks){
      s16x8 af  = *(const s16x8*)&Al[(mt*16 + (l & 15))*72 + ks*32 + (l >> 4)*8];
      s16x8 bf0 = *(const s16x8*)&Bl[((np2*2    )*16 + (l & 15))*72 + ks*32 + (l >> 4)*8];
      s16x8 bf1 = *(const s16x8*)&Bl[((np2*2 + 1)*16 + (l & 15))*72 + ks*32 + (l >> 4)*8];
      acc0 = __builtin_amdgcn_mfma_f32_16x16x32_bf16(af, bf0, acc0, 0, 0, 0);
      acc1 = __builtin_amdgcn_mfma_f32_16x16x32_bf16(af, bf1, acc1, 0, 0, 0);
    }
  }
  int col0 = np2*32 + (l & 15), col1 = col0 + 16;
  float lb0 = lb[col0], lb1 = lb[col1];
  float s0 = 0.f, q0 = 0.f, s1 = 0.f, q1 = 0.f;
  if (t < 64){ cps[t] = 0.f; cpq[t] = 0.f; }
  __syncthreads();
  #pragma unroll
  for (int r = 0; r < 4; ++r){
    int row = rowbase + mt*16 + (l >> 4)*4 + r;
    float y0 = acc0[r] + lb0;
    float y1 = acc1[r] + lb1;
    yw[(size_t)row*64 + col0] = y0;
    yw[(size_t)row*64 + col1] = y1;
    s0 += y0; q0 += y0*y0; s1 += y1; q1 += y1*y1;
  }
  atomicAdd(&cps[col0], s0); atomicAdd(&cpq[col0], q0);
  atomicAdd(&cps[col1], s1); atomicAdd(&cpq[col1], q1);
  __syncthreads();
  if (t < 64){
    PL[blockIdx.x*128 + t]      = cps[t];
    PL[blockIdx.x*128 + 64 + t] = cpq[t];
  }
}

// ---------------- k_redF ----------------
__global__ __launch_bounds__(128) void k_redF(const float* PL, float* SL){
  int t = threadIdx.x;
  float s = 0.f;
  for (int b = 0; b < 512; ++b) s += PL[b*128 + t];
  SL[t] = s;
}

// ---------------- k_final ----------------
__global__ __launch_bounds__(256) void k_final(const float* yw, const float* SL,
                                               const float* gl, const float* bl, float* out){
  int e = (blockIdx.x * 256 + threadIdx.x) * 4;
  int o = e & 63;
  f32x4 y = *(const f32x4*)(yw + e);
  f32x4 r;
  #pragma unroll
  for (int j = 0; j < 4; ++j){
    float m = SL[o+j] * (1.f/16384.f);
    float v = SL[64+o+j] * (1.f/16384.f) - m*m;
    float a = gl[o+j] * rsqrtf(v + EPSF);
    float d = bl[o+j] - m*a;
    r[j] = fmaxf(0.f, a*y[j] + d);
  }
  *(f32x4*)(out + 49152 + e) = r;
}

extern "C" void kernel_launch(void* const* d_in, const int* in_sizes, int n_in,
                              void* d_out, int out_size, void* d_ws, size_t ws_size,
                              hipStream_t stream){
  (void)in_sizes; (void)n_in; (void)out_size; (void)ws_size;
  const float* xyz    = (const float*)d_in[0];
  const float* points = (const float*)d_in[1];
  const float* lc     = (const float*)d_in[2];
  const int*   nbrl   = (const int*)d_in[3];
  const int*   didx   = (const int*)d_in[4];
  const float* w0 = (const float*)d_in[5];
  const float* b0 = (const float*)d_in[6];
  const float* g0 = (const float*)d_in[7];
  const float* be0= (const float*)d_in[8];
  const float* w1 = (const float*)d_in[9];
  const float* b1 = (const float*)d_in[10];
  const float* g1 = (const float*)d_in[11];
  const float* be1= (const float*)d_in[12];
  const float* w2 = (const float*)d_in[13];
  const float* b2 = (const float*)d_in[14];
  const float* g2 = (const float*)d_in[15];
  const float* be2= (const float*)d_in[16];
  const float* gc = (const float*)d_in[17];
  const float* bc = (const float*)d_in[18];
  const float* lw = (const float*)d_in[19];
  const float* lb = (const float*)d_in[20];
  const float* gl = (const float*)d_in[21];
  const float* bl = (const float*)d_in[22];
  float* out = (float*)d_out;
  char* ws = (char*)d_ws;

  float* F   = (float*)ws;           // 1536
  float* SL  = F + 1536;             // 128
  float* AC  = SL + 128;             // 4096
  float* DC  = AC + 4096;            // 4096
  float* PA  = DC + 4096;            // 32768
  float* PB1 = PA + 32768;           // 139264
  float* PB2 = PB1 + 139264;         // 139264
  float* PL  = PB2 + 139264;         // 65536
  u16*  w1Bg = (u16*)(PL + 65536);   // 512 u16
  u16*  w2Bg = w1Bg + 512;           // 2048 u16
  float* PC  = (float*)(ws + 4194304);                        // 8 MB
  u16*  npw  = (u16*)(ws + 4194304 + 8388608);                // 128 MB bf16 (transposed)
  float* yw  = (float*)(ws + 4194304 + 8388608 + 134217728);  // 4 MB f32
  u16*  lwbt = (u16*)(ws + 4194304 + 8388608 + 134217728 + 4194304); // 512 KB (permuted)
  u16*  ptsw = (u16*)(ws + 4194304 + 8388608 + 134217728 + 4194304 + 1048576); // 8 MB bf16

  k_init  <<<640,   256, 0, stream>>>(xyz, didx, out, lw, lwbt, points, ptsw);
  k_stat0 <<<512,   256, 0, stream>>>(lc, PA);
  k_red0  <<<1,     256, 0, stream>>>(PA, w0, b0, g0, be0, F);
  k_statG1<<<SGBLK, 256, 0, stream>>>(lc, F, PB1);
  k_red1  <<<1,     256, 0, stream>>>(PB1, w1, b1, g1, be1, F, w1Bg);
  k_statG2<<<SGBLK, 256, 0, stream>>>(lc, F, w1Bg, PB2);
  k_red2  <<<1,     256, 0, stream>>>(PB2, w2, b2, g2, be2, F, w2Bg);
  k_main  <<<16384, 256, 0, stream>>>(lc, nbrl, ptsw, F, w1Bg, w2Bg, npw);
  k_statC <<<256,   256, 0, stream>>>(npw, PC);
  k_finC  <<<16,    256, 0, stream>>>(PC, gc, bc, AC, DC);
  k_linear<<<512,   256, 0, stream>>>(npw, AC, DC, lwbt, lb, yw, PL);
  k_redF  <<<1,     128, 0, stream>>>(PL, SL);
  k_final <<<1024,  256, 0, stream>>>(yw, SL, gl, bl, out);
}

// Round 19
// 251.795 us; speedup vs baseline: 7.0090x; 1.0274x over previous
//
#include <hip/hip_runtime.h>
#include <hip/hip_bf16.h>

#define BB 16
#define NN 4096
#define NPOINTS 1024
#define KK 32
#define NPTS (BB*NPOINTS)        // 16384
#define NWN  (BB*NPOINTS*KK)     // 524288
#define EPSF 1e-5f
#define SGBLK 512
#define SGIT  4

typedef unsigned short u16;
typedef u16  u16x8 __attribute__((ext_vector_type(8)));
typedef u16  u16x4 __attribute__((ext_vector_type(4)));
typedef short s16x8 __attribute__((ext_vector_type(8)));
typedef float f32x4 __attribute__((ext_vector_type(4)));
typedef float f32x4u __attribute__((ext_vector_type(4), aligned(4)));

__device__ __forceinline__ float bf(u16 u){
  union { unsigned int i; float f; } v; v.i = ((unsigned int)u) << 16; return v.f;
}
__device__ __forceinline__ u16 f2b(float f){
  __hip_bfloat16 h = __float2bfloat16(f);
  union { __hip_bfloat16 hh; u16 u; } v; v.hh = h; return v.u;
}

// F layout (folded weights): [0..47] w0f, [48..63] b0f, [64..319] w1f,
// [320..335] b1f, [336..1359] w2f, [1360..1423] b2f
// npw: transposed position space q = o*64 + i  (original channel ch = i*64 + o)
// ptsw[B*N][64] bf16: pre-converted concat(points, xyz) rows
// Gr LDS: K-major, 16B k-blocks XOR-swizzled by (ch>>3)&3
// NOTE (round 15): device atomics bypass L2 on MI355X -> keep stats streaming.

// ---------------- k_init: newxyz (0..63) + lwbt (64..127) + ptsw build (128..639) ----------------
__global__ __launch_bounds__(256) void k_init(const float* xyz, const int* didx, float* out,
                                              const float* lw, u16* lwbt,
                                              const float* points, u16* ptsw){
  int t = threadIdx.x;
  if (blockIdx.x < 64){
    int p = blockIdx.x * 256 + t;
    int b = p >> 10;
    int idx = didx[p];
    const float* src = xyz + ((size_t)(b * NN + idx)) * 3;
    float* dst = out + (size_t)p * 3;
    dst[0] = src[0]; dst[1] = src[1]; dst[2] = src[2];
  } else if (blockIdx.x < 128){
    __shared__ float T[64][65];
    int ib = blockIdx.x - 64;
    int kb = ib * 64;
    {
      int k = t >> 2, c4 = t & 3;
      #pragma unroll
      for (int j = 0; j < 4; ++j)
        *(f32x4*)&T[k][c4*16 + j*4] = *(const f32x4*)(lw + (size_t)(kb + k)*64 + c4*16 + j*4);
    }
    __syncthreads();
    {
      int n = t >> 2, k4 = t & 3;
      #pragma unroll
      for (int j = 0; j < 16; ++j){
        int k = k4*16 + j;
        lwbt[(size_t)n*4096 + k*64 + ib] = f2b(T[k][n]);
      }
    }
  } else {
    int gid0 = (blockIdx.x - 128) * 256 + t;
    #pragma unroll
    for (int rep = 0; rep < 4; ++rep){
      int idx = gid0 + rep * 131072;
      int row = idx >> 3, c8 = idx & 7;
      const float* prow = points + (size_t)row * 61;
      u16x8 g;
      if (c8 < 7){
        f32x4 lo = *(const f32x4u*)(prow + c8*8);
        f32x4 hi = *(const f32x4u*)(prow + c8*8 + 4);
        g[0]=f2b(lo.x); g[1]=f2b(lo.y); g[2]=f2b(lo.z); g[3]=f2b(lo.w);
        g[4]=f2b(hi.x); g[5]=f2b(hi.y); g[6]=f2b(hi.z); g[7]=f2b(hi.w);
      } else {
        const float* xr = xyz + (size_t)row * 3;
        f32x4 lo = *(const f32x4u*)(prow + 56);
        g[0]=f2b(lo.x); g[1]=f2b(lo.y); g[2]=f2b(lo.z); g[3]=f2b(lo.w);
        g[4]=f2b(prow[60]);
        g[5]=f2b(xr[0]); g[6]=f2b(xr[1]); g[7]=f2b(xr[2]);
      }
      *(u16x8*)(ptsw + (size_t)row*64 + c8*8) = g;
    }
  }
}

// ---------------- k_stat0 ----------------
__global__ __launch_bounds__(256) void k_stat0(const float* lc, float* PA){
  int t = threadIdx.x;
  float a[9];
  #pragma unroll
  for (int r = 0; r < 9; ++r) a[r] = 0.f;
  size_t base = (size_t)blockIdx.x * 1024 + t;
  for (int ip = 0; ip < 4; ++ip){
    size_t p = base + (size_t)ip * 256;
    float x0 = lc[p*3], x1 = lc[p*3+1], x2 = lc[p*3+2];
    a[0]+=x0; a[1]+=x1; a[2]+=x2;
    a[3]+=x0*x0; a[4]+=x0*x1; a[5]+=x0*x2;
    a[6]+=x1*x1; a[7]+=x1*x2; a[8]+=x2*x2;
  }
  #pragma unroll
  for (int m = 1; m < 64; m <<= 1){
    #pragma unroll
    for (int r = 0; r < 9; ++r) a[r] += __shfl_xor(a[r], m);
  }
  if ((t & 63) == 0){
    float* dst = PA + (size_t)(blockIdx.x*4 + (t>>6)) * 16;
    f32x4 v0 = {a[0],a[1],a[2],a[3]}, v1 = {a[4],a[5],a[6],a[7]}, v2 = {a[8],0.f,0.f,0.f};
    *(f32x4*)dst = v0; *(f32x4*)(dst+4) = v1; *(f32x4*)(dst+8) = v2;
  }
}

// ---------------- k_red0 ----------------
__global__ __launch_bounds__(256) void k_red0(const float* PA, const float* w0, const float* b0,
                                              const float* g0, const float* be0, float* F){
  __shared__ float ms[12];
  __shared__ float a0sh[16];
  int t = threadIdx.x;
  if (t < 12){
    float s0=0,s1=0,s2=0,s3=0;
    const float* p = PA + t;
    for (int r = 0; r < 2048; r += 4){
      s0 += p[(size_t)(r+0)*16]; s1 += p[(size_t)(r+1)*16];
      s2 += p[(size_t)(r+2)*16]; s3 += p[(size_t)(r+3)*16];
    }
    ms[t] = (s0+s1)+(s2+s3);
  }
  __syncthreads();
  if (t < 16){
    float wx = w0[t*3], wy = w0[t*3+1], wz = w0[t*3+2], bb = b0[t];
    float lin = wx*ms[0] + wy*ms[1] + wz*ms[2];
    float quad = wx*wx*ms[3] + wy*wy*ms[6] + wz*wz*ms[8]
               + 2.f*(wx*wy*ms[4] + wx*wz*ms[5] + wy*wz*ms[7]);
    float S = lin + (float)NWN * bb;
    float Q = quad + 2.f*bb*lin + (float)NWN*bb*bb;
    float m = S * (1.f/NWN);
    float v = Q * (1.f/NWN) - m*m;
    float a = g0[t] * rsqrtf(v + EPSF);
    float d = be0[t] - m*a;
    a0sh[t] = a;
    F[48+t] = a*bb + d;
  }
  __syncthreads();
  if (t < 48) F[t] = a0sh[t/3] * w0[t];
}

// ---------------- k_statG1: h0 Gram (VALU h0, MFMA Gram) ----------------
__global__ __launch_bounds__(256) void k_statG1(const float* lc, const float* F, float* PB){
  __shared__ f32x4 w0p[16];
  __shared__ __align__(16) u16 Ht[4][16*72];
  __shared__ float GS[4][16][17];
  __shared__ float SHs[4][16];
  int t = threadIdx.x;
  int w = t >> 6, l = t & 63;
  if (t < 16){
    f32x4 wv = {F[t*3], F[t*3+1], F[t*3+2], F[48+t]};
    w0p[t] = wv;
  }
  __syncthreads();
  f32x4 acc = {0.f,0.f,0.f,0.f};
  float sh[16];
  #pragma unroll
  for (int r = 0; r < 16; ++r) sh[r] = 0.f;
  u16* Hw = &Ht[w][0];
  for (int it = 0; it < SGIT; ++it){
    size_t p = (size_t)blockIdx.x * (SGIT*256) + (size_t)it*256 + w*64 + l;
    float x0 = lc[p*3], x1 = lc[p*3+1], x2 = lc[p*3+2];
    float h[16];
    #pragma unroll
    for (int oc = 0; oc < 16; ++oc){
      f32x4 wv = w0p[oc];
      h[oc] = fmaxf(0.f, wv.x*x0 + wv.y*x1 + wv.z*x2 + wv.w);
      sh[oc] += h[oc];
    }
    #pragma unroll
    for (int c = 0; c < 16; ++c) Hw[c*72 + l] = f2b(h[c]);
    __syncthreads();
    #pragma unroll
    for (int tt = 0; tt < 2; ++tt){
      s16x8 af = *(const s16x8*)&Hw[(l & 15)*72 + tt*32 + (l >> 4)*8];
      acc = __builtin_amdgcn_mfma_f32_16x16x32_bf16(af, af, acc, 0, 0, 0);
    }
    __syncthreads();
  }
  #pragma unroll
  for (int r = 0; r < 4; ++r)
    GS[w][(l>>4)*4 + r][l & 15] = acc[r];
  #pragma unroll
  for (int m = 1; m < 64; m <<= 1){
    #pragma unroll
    for (int r = 0; r < 16; ++r) sh[r] += __shfl_xor(sh[r], m);
  }
  if (l == 0){
    #pragma unroll
    for (int r = 0; r < 16; ++r) SHs[w][r] = sh[r];
  }
  __syncthreads();
  {
    int i = t >> 4, j = t & 15;
    float g = GS[0][i][j] + GS[1][i][j] + GS[2][i][j] + GS[3][i][j];
    PB[(size_t)blockIdx.x*272 + t] = g;
    if (t < 16)
      PB[(size_t)blockIdx.x*272 + 256 + t] = SHs[0][t]+SHs[1][t]+SHs[2][t]+SHs[3][t];
  }
}

// ---------------- k_statG2: h1 Gram (MFMA h1 via w1Bg + MFMA Gram) ----------------
__global__ __launch_bounds__(256) void k_statG2(const float* lc, const float* F,
                                                const u16* w1Bg, float* PB){
  __shared__ f32x4 w0p[16];
  __shared__ __align__(16) u16 Ht0[4][64*40];
  __shared__ __align__(16) u16 Ht1[4][16*72];
  __shared__ float GS[4][16][17];
  __shared__ float SHs[4][16];
  int t = threadIdx.x;
  int w = t >> 6, l = t & 63;
  if (t < 16){
    f32x4 wv = {F[t*3], F[t*3+1], F[t*3+2], F[48+t]};
    w0p[t] = wv;
  }
  s16x8 w1B = *(const s16x8*)&w1Bg[l*8];
  float b1f = F[320 + (l & 15)];
  u16* H0w = &Ht0[w][0];
  u16* H1w = &Ht1[w][0];
  {
    u16x8 z8 = {0,0,0,0,0,0,0,0};
    *(u16x8*)&H0w[l*40 + 16] = z8;
    *(u16x8*)&H0w[l*40 + 24] = z8;
  }
  __syncthreads();
  f32x4 acc = {0.f,0.f,0.f,0.f};
  float shloc = 0.f;
  for (int it = 0; it < SGIT; ++it){
    size_t p = (size_t)blockIdx.x * (SGIT*256) + (size_t)it*256 + w*64 + l;
    float x0 = lc[p*3], x1 = lc[p*3+1], x2 = lc[p*3+2];
    u16x8 p0, p1;
    #pragma unroll
    for (int oc = 0; oc < 8; ++oc){
      f32x4 wv = w0p[oc];
      p0[oc] = f2b(fmaxf(0.f, wv.x*x0 + wv.y*x1 + wv.z*x2 + wv.w));
    }
    #pragma unroll
    for (int oc = 0; oc < 8; ++oc){
      f32x4 wv = w0p[8+oc];
      p1[oc] = f2b(fmaxf(0.f, wv.x*x0 + wv.y*x1 + wv.z*x2 + wv.w));
    }
    *(u16x8*)&H0w[l*40]     = p0;
    *(u16x8*)&H0w[l*40 + 8] = p1;
    __syncthreads();
    #pragma unroll
    for (int mt = 0; mt < 4; ++mt){
      s16x8 af = *(const s16x8*)&H0w[(mt*16 + (l & 15))*40 + (l >> 4)*8];
      f32x4 c = {b1f, b1f, b1f, b1f};
      c = __builtin_amdgcn_mfma_f32_16x16x32_bf16(af, w1B, c, 0, 0, 0);
      #pragma unroll
      for (int r = 0; r < 4; ++r){
        float v = fmaxf(0.f, c[r]);
        shloc += v;
        H1w[(l & 15)*72 + mt*16 + (l >> 4)*4 + r] = f2b(v);
      }
    }
    __syncthreads();
    #pragma unroll
    for (int tt = 0; tt < 2; ++tt){
      s16x8 afg = *(const s16x8*)&H1w[(l & 15)*72 + tt*32 + (l >> 4)*8];
      acc = __builtin_amdgcn_mfma_f32_16x16x32_bf16(afg, afg, acc, 0, 0, 0);
    }
    __syncthreads();
  }
  #pragma unroll
  for (int r = 0; r < 4; ++r)
    GS[w][(l>>4)*4 + r][l & 15] = acc[r];
  shloc += __shfl_xor(shloc, 16);
  shloc += __shfl_xor(shloc, 32);
  if (l < 16) SHs[w][l] = shloc;
  __syncthreads();
  {
    int i = t >> 4, j = t & 15;
    float g = GS[0][i][j] + GS[1][i][j] + GS[2][i][j] + GS[3][i][j];
    PB[(size_t)blockIdx.x*272 + t] = g;
    if (t < 16)
      PB[(size_t)blockIdx.x*272 + 256 + t] = SHs[0][t]+SHs[1][t]+SHs[2][t]+SHs[3][t];
  }
}

// ---------------- k_red1 ----------------
__global__ __launch_bounds__(256) void k_red1(const float* PB, const float* w1, const float* b1,
                                              const float* g1, const float* be1, float* F,
                                              u16* w1Bg){
  __shared__ float red[272];
  __shared__ float a1sh[16];
  int t = threadIdx.x;
  for (int e = t; e < 272; e += 256){
    float s = 0.f;
    for (int r = 0; r < SGBLK; ++r) s += PB[(size_t)r*272 + e];
    red[e] = s;
  }
  __syncthreads();
  if (t < 16){
    float wv[16];
    #pragma unroll
    for (int ic = 0; ic < 16; ++ic) wv[ic] = w1[t*16+ic];
    float lin = 0.f;
    #pragma unroll
    for (int ic = 0; ic < 16; ++ic) lin += wv[ic]*red[256+ic];
    float quad = 0.f;
    for (int i = 0; i < 16; ++i){
      float ri = 0.f;
      #pragma unroll
      for (int j = 0; j < 16; ++j) ri += wv[j]*red[i*16+j];
      quad += wv[i]*ri;
    }
    float bb = b1[t];
    float S = lin + (float)NWN * bb;
    float Q = quad + 2.f*bb*lin + (float)NWN*bb*bb;
    float m = S * (1.f/NWN);
    float v = Q * (1.f/NWN) - m*m;
    float a = g1[t] * rsqrtf(v + EPSF);
    float d = be1[t] - m*a;
    a1sh[t] = a;
    F[320+t] = a*bb + d;
  }
  __syncthreads();
  F[64 + t] = a1sh[t >> 4] * w1[t];
  if (t < 64){
    int oc = t & 15, icb = (t >> 4) * 8;
    u16x8 fr;
    #pragma unroll
    for (int j = 0; j < 8; ++j){
      int ic = icb + j;
      fr[j] = (ic < 16) ? f2b(a1sh[oc] * w1[oc*16 + ic]) : (u16)0;
    }
    *(u16x8*)&w1Bg[t*8] = fr;
  }
}

// ---------------- k_red2 ----------------
__global__ __launch_bounds__(256) void k_red2(const float* PB, const float* w2, const float* b2,
                                              const float* g2, const float* be2, float* F,
                                              u16* w2Bg){
  __shared__ float red[272];
  __shared__ float a2sh[64];
  int t = threadIdx.x;
  for (int e = t; e < 272; e += 256){
    float s = 0.f;
    for (int r = 0; r < SGBLK; ++r) s += PB[(size_t)r*272 + e];
    red[e] = s;
  }
  __syncthreads();
  if (t < 64){
    float wv[16];
    #pragma unroll
    for (int ic = 0; ic < 16; ++ic) wv[ic] = w2[t*16+ic];
    float lin = 0.f;
    #pragma unroll
    for (int ic = 0; ic < 16; ++ic) lin += wv[ic]*red[256+ic];
    float quad = 0.f;
    for (int i = 0; i < 16; ++i){
      float ri = 0.f;
      #pragma unroll
      for (int j = 0; j < 16; ++j) ri += wv[j]*red[i*16+j];
      quad += wv[i]*ri;
    }
    float bb = b2[t];
    float S = lin + (float)NWN * bb;
    float Q = quad + 2.f*bb*lin + (float)NWN*bb*bb;
    float m = S * (1.f/NWN);
    float v = Q * (1.f/NWN) - m*m;
    float a = g2[t] * rsqrtf(v + EPSF);
    float d = be2[t] - m*a;
    a2sh[t] = a;
    F[1360+t] = a*bb + d;
  }
  __syncthreads();
  for (int i = t; i < 1024; i += 256) F[336+i] = a2sh[i >> 4] * w2[i];
  {
    int ot = t >> 6, lane = t & 63;
    int oc = ot*16 + (lane & 15), icb = ((lane >> 4)) * 8;
    u16x8 fr;
    #pragma unroll
    for (int j = 0; j < 8; ++j){
      int ic = icb + j;
      fr[j] = (ic < 16) ? f2b(a2sh[oc] * w2[oc*16 + ic]) : (u16)0;
    }
    *(u16x8*)&w2Bg[t*8] = fr;
  }
}

// ---------------- K5: TWO points per block — MFMA WeightNet + MFMA matmul, 3 barriers ----------------
__global__ __launch_bounds__(256) void k_main(const float* lcg, const int* nbrg,
    const u16* ptsw, const float* F,
    const u16* w1Bg, const u16* w2Bg,
    u16* npw){
  __shared__ __align__(16) u16 Gr[2][64*40];        // swizzled K-major per point
  __shared__ __align__(16) u16 Wr[2][64*40];
  __shared__ __align__(16) u16 H0bf[2][32*40];
  __shared__ __align__(16) u16 H1bf[2][32*40];
  int t = threadIdx.x;
  int w = t >> 6, l = t & 63;
  int p0 = blockIdx.x * 2;
  // register frags (L2-hot)
  s16x8 w1B  = *(const s16x8*)&w1Bg[l*8];
  s16x8 w2B0 = *(const s16x8*)&w2Bg[(0*64 + l)*8];
  s16x8 w2B1 = *(const s16x8*)&w2Bg[(1*64 + l)*8];
  s16x8 w2B2 = *(const s16x8*)&w2Bg[(2*64 + l)*8];
  s16x8 w2B3 = *(const s16x8*)&w2Bg[(3*64 + l)*8];
  float b1f  = F[320 + (l & 15)];
  float b2f0 = F[1360 +  0 + (l & 15)];
  float b2f1 = F[1360 + 16 + (l & 15)];
  float b2f2 = F[1360 + 32 + (l & 15)];
  float b2f3 = F[1360 + 48 + (l & 15)];
  // per-thread w0 rows (oc0, oc0+1) in registers — no LDS staging, no guard barrier
  int oc0 = (t & 7) * 2;
  f32x4 w0a = {F[oc0*3], F[oc0*3+1], F[oc0*3+2], F[48+oc0]};
  f32x4 w0b = {F[oc0*3+3], F[oc0*3+4], F[oc0*3+5], F[48+oc0+1]};
  // zero-pad ic 16..31 rows (both points, both tiles)
  {
    int k = t >> 3, c = 16 + (t & 7)*2;
    *(unsigned int*)&H0bf[0][k*40 + c] = 0u;
    *(unsigned int*)&H0bf[1][k*40 + c] = 0u;
    *(unsigned int*)&H1bf[0][k*40 + c] = 0u;
    *(unsigned int*)&H1bf[1][k*40 + c] = 0u;
  }
  // gather both points -> Gr swizzled K-major
  {
    int kg = w*8 + (l >> 3), c8 = l & 7;
    int kphys = ((w ^ (c8 & 3)) << 3) + (l >> 3);
    #pragma unroll
    for (int pt = 0; pt < 2; ++pt){
      int point = p0 + pt;
      int bbp = point >> 10;
      int n = nbrg[(size_t)point*32 + kg];
      u16x8 g = *(const u16x8*)(ptsw + (size_t)(bbp * NN + n)*64 + c8*8);
      #pragma unroll
      for (int j = 0; j < 8; ++j)
        Gr[pt][(c8*8 + j)*40 + kphys] = g[j];
    }
  }
  // H0 both points (w0 in registers; wave-private rows not needed — each thread owns (k, oc0..oc0+1))
  {
    int k = t >> 3;
    #pragma unroll
    for (int pt = 0; pt < 2; ++pt){
      const float* xp = lcg + (size_t)(p0 + pt)*96 + k*3;
      float x0 = xp[0], x1 = xp[1], x2 = xp[2];
      H0bf[pt][k*40 + oc0]     = f2b(fmaxf(0.f, w0a.x*x0 + w0a.y*x1 + w0a.z*x2 + w0a.w));
      H0bf[pt][k*40 + oc0 + 1] = f2b(fmaxf(0.f, w0b.x*x0 + w0b.y*x1 + w0b.z*x2 + w0b.w));
    }
  }
  __syncthreads();   // (1) H0bf + pads ready
  // H1: wave w -> pt = w>>1, kt = w&1  (all 4 waves active)
  {
    int pt = w >> 1, kt = w & 1;
    s16x8 af = *(const s16x8*)&H0bf[pt][(kt*16 + (l & 15))*40 + (l >> 4)*8];
    f32x4 acc = {b1f, b1f, b1f, b1f};
    acc = __builtin_amdgcn_mfma_f32_16x16x32_bf16(af, w1B, acc, 0, 0, 0);
    #pragma unroll
    for (int r = 0; r < 4; ++r)
      H1bf[pt][(kt*16 + (l >> 4)*4 + r)*40 + (l & 15)] = f2b(fmaxf(0.f, acc[r]));
  }
  __syncthreads();   // (2) H1bf ready
  // W: wave w -> pt = w&1, kt = w>>1; all 4 o-tiles (4 MFMAs/wave)
  {
    int pt = w & 1, kt = w >> 1;
    s16x8 af = *(const s16x8*)&H1bf[pt][(kt*16 + (l & 15))*40 + (l >> 4)*8];
    int kbase = kt*16 + (l >> 4)*4;
    f32x4 a0c = {b2f0,b2f0,b2f0,b2f0};
    a0c = __builtin_amdgcn_mfma_f32_16x16x32_bf16(af, w2B0, a0c, 0, 0, 0);
    u16x4 s0v; s0v[0]=f2b(fmaxf(0.f,a0c[0])); s0v[1]=f2b(fmaxf(0.f,a0c[1]));
    s0v[2]=f2b(fmaxf(0.f,a0c[2])); s0v[3]=f2b(fmaxf(0.f,a0c[3]));
    *(u16x4*)&Wr[pt][( 0 + (l & 15))*40 + kbase] = s0v;
    f32x4 a1c = {b2f1,b2f1,b2f1,b2f1};
    a1c = __builtin_amdgcn_mfma_f32_16x16x32_bf16(af, w2B1, a1c, 0, 0, 0);
    u16x4 s1v; s1v[0]=f2b(fmaxf(0.f,a1c[0])); s1v[1]=f2b(fmaxf(0.f,a1c[1]));
    s1v[2]=f2b(fmaxf(0.f,a1c[2])); s1v[3]=f2b(fmaxf(0.f,a1c[3]));
    *(u16x4*)&Wr[pt][(16 + (l & 15))*40 + kbase] = s1v;
    f32x4 a2c = {b2f2,b2f2,b2f2,b2f2};
    a2c = __builtin_amdgcn_mfma_f32_16x16x32_bf16(af, w2B2, a2c, 0, 0, 0);
    u16x4 s2v; s2v[0]=f2b(fmaxf(0.f,a2c[0])); s2v[1]=f2b(fmaxf(0.f,a2c[1]));
    s2v[2]=f2b(fmaxf(0.f,a2c[2])); s2v[3]=f2b(fmaxf(0.f,a2c[3]));
    *(u16x4*)&Wr[pt][(32 + (l & 15))*40 + kbase] = s2v;
    f32x4 a3c = {b2f3,b2f3,b2f3,b2f3};
    a3c = __builtin_amdgcn_mfma_f32_16x16x32_bf16(af, w2B3, a3c, 0, 0, 0);
    u16x4 s3v; s3v[0]=f2b(fmaxf(0.f,a3c[0])); s3v[1]=f2b(fmaxf(0.f,a3c[1]));
    s3v[2]=f2b(fmaxf(0.f,a3c[2])); s3v[3]=f2b(fmaxf(0.f,a3c[3]));
    *(u16x4*)&Wr[pt][(48 + (l & 15))*40 + kbase] = s3v;
  }
  __syncthreads();   // (3) Gr, Wr ready
  // np = G^T W: wave w owns o-tile w, both points (8 MFMAs/wave)
  {
    int li = l & 15, lkb = l >> 4, lr = (l >> 4) * 4;
    #pragma unroll
    for (int pt = 0; pt < 2; ++pt){
      s16x8 bfrag = *(const s16x8*)&Wr[pt][(w*16 + li)*40 + lkb*8];
      size_t obase = (size_t)(p0 + pt)*4096 + (size_t)(w*16 + li)*64 + lr;
      #pragma unroll
      for (int it = 0; it < 4; ++it){
        int ch = it*16 + li;
        int key = (ch >> 3) & 3;
        s16x8 afrag = *(const s16x8*)&Gr[pt][ch*40 + ((lkb ^ key) << 3)];
        f32x4 z = {0.f, 0.f, 0.f, 0.f};
        f32x4 d = __builtin_amdgcn_mfma_f32_16x16x32_bf16(afrag, bfrag, z, 0, 0, 0);
        u16x4 st;
        st[0] = f2b(d[0]); st[1] = f2b(d[1]); st[2] = f2b(d[2]); st[3] = f2b(d[3]);
        *(u16x4*)(npw + obase + it*16) = st;
      }
    }
  }
}

// ---------------- k_statC ----------------
__global__ __launch_bounds__(256) void k_statC(const u16* npw, float* PC){
  int t = threadIdx.x;
  float s[16], q[16];
  #pragma unroll
  for (int j = 0; j < 16; ++j){ s[j] = 0.f; q[j] = 0.f; }
  size_t rowbase = (size_t)blockIdx.x * 64;
  for (int p = 0; p < 64; ++p){
    const u16* row = npw + (rowbase + p) * 4096 + t * 16;
    u16x8 a = *(const u16x8*)row;
    u16x8 b = *(const u16x8*)(row + 8);
    #pragma unroll
    for (int j = 0; j < 8; ++j){ float v = bf(a[j]); s[j]   += v; q[j]   += v*v; }
    #pragma unroll
    for (int j = 0; j < 8; ++j){ float v = bf(b[j]); s[8+j] += v; q[8+j] += v*v; }
  }
  float* dst = PC + (size_t)blockIdx.x * 8192 + t * 16;
  #pragma unroll
  for (int j = 0; j < 16; ++j){ dst[j] = s[j]; dst[4096 + j] = q[j]; }
}

// ---------------- k_finC (position space; gc/bc permuted) ----------------
__global__ __launch_bounds__(256) void k_finC(const float* PC, const float* gc, const float* bc,
                                              float* AC, float* DC){
  int qpos = blockIdx.x * 256 + threadIdx.x;
  float s = 0.f, q = 0.f;
  for (int r = 0; r < 256; ++r){
    s += PC[(size_t)r * 8192 + qpos];
    q += PC[(size_t)r * 8192 + 4096 + qpos];
  }
  int ch = (qpos & 63)*64 + (qpos >> 6);
  float m = s * (1.f/16384.f);
  float v = q * (1.f/16384.f) - m*m;
  float a = gc[ch] * rsqrtf(v + EPSF);
  AC[qpos] = a; DC[qpos] = bc[ch] - m*a;
}

// ---------------- k_linear ----------------
__global__ __launch_bounds__(256) void k_linear(const u16* npw, const float* AC, const float* DC,
                                                const u16* lwbt, const float* lb, float* yw,
                                                float* PL){
  __shared__ u16 Al[32*72];
  __shared__ u16 Bl[64*72];
  __shared__ float cps[64], cpq[64];
  int t = threadIdx.x;
  int w = t >> 6, l = t & 63;
  int rowbase = blockIdx.x * 32;
  int mt = w & 1, np2 = w >> 1;
  f32x4 acc0 = {0.f,0.f,0.f,0.f}, acc1 = acc0;
  for (int kb = 0; kb < 4096; kb += 64){
    __syncthreads();
    {
      int r = t >> 3, c8 = t & 7;
      int kk = kb + c8*8;
      u16x8 u = *(const u16x8*)(npw + (size_t)(rowbase + r)*4096 + kk);
      f32x4 alo = *(const f32x4*)(AC + kk), ahi = *(const f32x4*)(AC + kk + 4);
      f32x4 dlo = *(const f32x4*)(DC + kk), dhi = *(const f32x4*)(DC + kk + 4);
      u16x8 o;
      o[0] = f2b(fmaxf(0.f, alo.x*bf(u[0]) + dlo.x));
      o[1] = f2b(fmaxf(0.f, alo.y*bf(u[1]) + dlo.y));
      o[2] = f2b(fmaxf(0.f, alo.z*bf(u[2]) + dlo.z));
      o[3] = f2b(fmaxf(0.f, alo.w*bf(u[3]) + dlo.w));
      o[4] = f2b(fmaxf(0.f, ahi.x*bf(u[4]) + dhi.x));
      o[5] = f2b(fmaxf(0.f, ahi.y*bf(u[5]) + dhi.y));
      o[6] = f2b(fmaxf(0.f, ahi.z*bf(u[6]) + dhi.z));
      o[7] = f2b(fmaxf(0.f, ahi.w*bf(u[7]) + dhi.w));
      *(u16x8*)&Al[r*72 + c8*8] = o;
    }
    #pragma unroll
    for (int jj = 0; jj < 2; ++jj){
      int n = (t >> 3) + jj*32, c8 = t & 7;
      u16x8 u = *(const u16x8*)(lwbt + (size_t)n*4096 + kb + c8*8);
      *(u16x8*)&Bl[n*72 + c8*8] = u;
    }
    __syncthreads();
    #pragma unroll
    for (int ks = 0; ks < 2; ++ks){
      s16x8 af  = *(const s16x8*)&Al[(mt*16 + (l & 15))*72 + ks*32 + (l >> 4)*8];
      s16x8 bf0 = *(const s16x8*)&Bl[((np2*2    )*16 + (l & 15))*72 + ks*32 + (l >> 4)*8];
      s16x8 bf1 = *(const s16x8*)&Bl[((np2*2 + 1)*16 + (l & 15))*72 + ks*32 + (l >> 4)*8];
      acc0 = __builtin_amdgcn_mfma_f32_16x16x32_bf16(af, bf0, acc0, 0, 0, 0);
      acc1 = __builtin_amdgcn_mfma_f32_16x16x32_bf16(af, bf1, acc1, 0, 0, 0);
    }
  }
  int col0 = np2*32 + (l & 15), col1 = col0 + 16;
  float lb0 = lb[col0], lb1 = lb[col1];
  float s0 = 0.f, q0 = 0.f, s1 = 0.f, q1 = 0.f;
  if (t < 64){ cps[t] = 0.f; cpq[t] = 0.f; }
  __syncthreads();
  #pragma unroll
  for (int r = 0; r < 4; ++r){
    int row = rowbase + mt*16 + (l >> 4)*4 + r;
    float y0 = acc0[r] + lb0;
    float y1 = acc1[r] + lb1;
    yw[(size_t)row*64 + col0] = y0;
    yw[(size_t)row*64 + col1] = y1;
    s0 += y0; q0 += y0*y0; s1 += y1; q1 += y1*y1;
  }
  atomicAdd(&cps[col0], s0); atomicAdd(&cpq[col0], q0);
  atomicAdd(&cps[col1], s1); atomicAdd(&cpq[col1], q1);
  __syncthreads();
  if (t < 64){
    PL[blockIdx.x*128 + t]      = cps[t];
    PL[blockIdx.x*128 + 64 + t] = cpq[t];
  }
}

// ---------------- k_redF ----------------
__global__ __launch_bounds__(128) void k_redF(const float* PL, float* SL){
  int t = threadIdx.x;
  float s = 0.f;
  for (int b = 0; b < 512; ++b) s += PL[b*128 + t];
  SL[t] = s;
}

// ---------------- k_final ----------------
__global__ __launch_bounds__(256) void k_final(const float* yw, const float* SL,
                                               const float* gl, const float* bl, float* out){
  int e = (blockIdx.x * 256 + threadIdx.x) * 4;
  int o = e & 63;
  f32x4 y = *(const f32x4*)(yw + e);
  f32x4 r;
  #pragma unroll
  for (int j = 0; j < 4; ++j){
    float m = SL[o+j] * (1.f/16384.f);
    float v = SL[64+o+j] * (1.f/16384.f) - m*m;
    float a = gl[o+j] * rsqrtf(v + EPSF);
    float d = bl[o+j] - m*a;
    r[j] = fmaxf(0.f, a*y[j] + d);
  }
  *(f32x4*)(out + 49152 + e) = r;
}

extern "C" void kernel_launch(void* const* d_in, const int* in_sizes, int n_in,
                              void* d_out, int out_size, void* d_ws, size_t ws_size,
                              hipStream_t stream){
  (void)in_sizes; (void)n_in; (void)out_size; (void)ws_size;
  const float* xyz    = (const float*)d_in[0];
  const float* points = (const float*)d_in[1];
  const float* lc     = (const float*)d_in[2];
  const int*   nbrl   = (const int*)d_in[3];
  const int*   didx   = (const int*)d_in[4];
  const float* w0 = (const float*)d_in[5];
  const float* b0 = (const float*)d_in[6];
  const float* g0 = (const float*)d_in[7];
  const float* be0= (const float*)d_in[8];
  const float* w1 = (const float*)d_in[9];
  const float* b1 = (const float*)d_in[10];
  const float* g1 = (const float*)d_in[11];
  const float* be1= (const float*)d_in[12];
  const float* w2 = (const float*)d_in[13];
  const float* b2 = (const float*)d_in[14];
  const float* g2 = (const float*)d_in[15];
  const float* be2= (const float*)d_in[16];
  const float* gc = (const float*)d_in[17];
  const float* bc = (const float*)d_in[18];
  const float* lw = (const float*)d_in[19];
  const float* lb = (const float*)d_in[20];
  const float* gl = (const float*)d_in[21];
  const float* bl = (const float*)d_in[22];
  float* out = (float*)d_out;
  char* ws = (char*)d_ws;

  float* F   = (float*)ws;           // 1536
  float* SL  = F + 1536;             // 128
  float* AC  = SL + 128;             // 4096
  float* DC  = AC + 4096;            // 4096
  float* PA  = DC + 4096;            // 32768
  float* PB1 = PA + 32768;           // 139264
  float* PB2 = PB1 + 139264;         // 139264
  float* PL  = PB2 + 139264;         // 65536
  u16*  w1Bg = (u16*)(PL + 65536);   // 512 u16
  u16*  w2Bg = w1Bg + 512;           // 2048 u16
  float* PC  = (float*)(ws + 4194304);                        // 8 MB
  u16*  npw  = (u16*)(ws + 4194304 + 8388608);                // 128 MB bf16 (transposed)
  float* yw  = (float*)(ws + 4194304 + 8388608 + 134217728);  // 4 MB f32
  u16*  lwbt = (u16*)(ws + 4194304 + 8388608 + 134217728 + 4194304); // 512 KB (permuted)
  u16*  ptsw = (u16*)(ws + 4194304 + 8388608 + 134217728 + 4194304 + 1048576); // 8 MB bf16

  k_init  <<<640,   256, 0, stream>>>(xyz, didx, out, lw, lwbt, points, ptsw);
  k_stat0 <<<512,   256, 0, stream>>>(lc, PA);
  k_red0  <<<1,     256, 0, stream>>>(PA, w0, b0, g0, be0, F);
  k_statG1<<<SGBLK, 256, 0, stream>>>(lc, F, PB1);
  k_red1  <<<1,     256, 0, stream>>>(PB1, w1, b1, g1, be1, F, w1Bg);
  k_statG2<<<SGBLK, 256, 0, stream>>>(lc, F, w1Bg, PB2);
  k_red2  <<<1,     256, 0, stream>>>(PB2, w2, b2, g2, be2, F, w2Bg);
  k_main  <<<8192,  256, 0, stream>>>(lc, nbrl, ptsw, F, w1Bg, w2Bg, npw);
  k_statC <<<256,   256, 0, stream>>>(npw, PC);
  k_finC  <<<16,    256, 0, stream>>>(PC, gc, bc, AC, DC);
  k_linear<<<512,   256, 0, stream>>>(npw, AC, DC, lwbt, lb, yw, PL);
  k_redF  <<<1,     128, 0, stream>>>(PL, SL);
  k_final <<<1024,  256, 0, stream>>>(yw, SL, gl, bl, out);
}